// Round 1
// baseline (1057.238 us; speedup 1.0000x reference)
//
#include <hip/hip_runtime.h>
#include <math.h>

#define EPSV 1e-5f
#define BB 4096
#define HH_MAIN 1024
#define HH_HYP 256
#define LDT 1280   // H + HH

__device__ __forceinline__ float sigf(float x){
  float e = expf(-fabsf(x));
  float r = 1.f/(1.f+e);
  return x>=0.f ? r : 1.f-r;
}

__device__ __forceinline__ float wave_sum(float v){
  #pragma unroll
  for (int m=32;m>0;m>>=1) v += __shfl_xor(v, m);
  return v;
}

// ---------------- GEMM (NT): C[m,n] = sum_k A[m,k]*B[n,k] (+bias[n]) (+=C if accflag)
// 128x128 tile, 256 threads, 8x8 per thread, TK=16. M,N multiples of 128, K multiple of 16.
#define TK 16
#define ALD 132

__global__ __launch_bounds__(256) void gemm_nt(
    const float* __restrict__ A, int lda,
    const float* __restrict__ Bm, int ldb,
    float* __restrict__ C, int ldc,
    int K, const float* __restrict__ bias, int accflag)
{
  __shared__ float As[TK*ALD];
  __shared__ float Bs[TK*ALD];
  const int tid = threadIdx.x;
  const int m0 = blockIdx.y*128, n0 = blockIdx.x*128;
  const int ar = tid>>2;          // 0..63
  const int ak = (tid&3)<<2;      // 0,4,8,12
  const int tx = tid&15, ty = tid>>4;
  float acc[8][8];
  #pragma unroll
  for (int i=0;i<8;i++)
    #pragma unroll
    for (int j=0;j<8;j++) acc[i][j]=0.f;

  const float* Ap0 = A + (size_t)(m0+ar)*lda + ak;
  const float* Ap1 = A + (size_t)(m0+ar+64)*lda + ak;
  const float* Bp0 = Bm + (size_t)(n0+ar)*ldb + ak;
  const float* Bp1 = Bm + (size_t)(n0+ar+64)*ldb + ak;

  for (int k0=0;k0<K;k0+=TK){
    float4 a0 = *(const float4*)(Ap0 + k0);
    float4 a1 = *(const float4*)(Ap1 + k0);
    float4 b0 = *(const float4*)(Bp0 + k0);
    float4 b1 = *(const float4*)(Bp1 + k0);
    __syncthreads();
    As[(ak+0)*ALD+ar]=a0.x; As[(ak+1)*ALD+ar]=a0.y; As[(ak+2)*ALD+ar]=a0.z; As[(ak+3)*ALD+ar]=a0.w;
    As[(ak+0)*ALD+ar+64]=a1.x; As[(ak+1)*ALD+ar+64]=a1.y; As[(ak+2)*ALD+ar+64]=a1.z; As[(ak+3)*ALD+ar+64]=a1.w;
    Bs[(ak+0)*ALD+ar]=b0.x; Bs[(ak+1)*ALD+ar]=b0.y; Bs[(ak+2)*ALD+ar]=b0.z; Bs[(ak+3)*ALD+ar]=b0.w;
    Bs[(ak+0)*ALD+ar+64]=b1.x; Bs[(ak+1)*ALD+ar+64]=b1.y; Bs[(ak+2)*ALD+ar+64]=b1.z; Bs[(ak+3)*ALD+ar+64]=b1.w;
    __syncthreads();
    #pragma unroll
    for (int kk=0;kk<TK;kk++){
      float4 av0 = *(const float4*)&As[kk*ALD + ty*4];
      float4 av1 = *(const float4*)&As[kk*ALD + ty*4 + 64];
      float4 bv0 = *(const float4*)&Bs[kk*ALD + tx*4];
      float4 bv1 = *(const float4*)&Bs[kk*ALD + tx*4 + 64];
      float a[8]={av0.x,av0.y,av0.z,av0.w,av1.x,av1.y,av1.z,av1.w};
      float b[8]={bv0.x,bv0.y,bv0.z,bv0.w,bv1.x,bv1.y,bv1.z,bv1.w};
      #pragma unroll
      for (int i=0;i<8;i++)
        #pragma unroll
        for (int j=0;j<8;j++) acc[i][j] += a[i]*b[j];
    }
  }
  #pragma unroll
  for (int ig=0;ig<2;ig++){
    #pragma unroll
    for (int i=0;i<4;i++){
      int row = m0 + ig*64 + ty*4 + i;
      #pragma unroll
      for (int jg=0;jg<2;jg++){
        int col = n0 + jg*64 + tx*4;
        float4 v;
        v.x=acc[ig*4+i][jg*4+0]; v.y=acc[ig*4+i][jg*4+1];
        v.z=acc[ig*4+i][jg*4+2]; v.w=acc[ig*4+i][jg*4+3];
        if (bias){ v.x+=bias[col]; v.y+=bias[col+1]; v.z+=bias[col+2]; v.w+=bias[col+3]; }
        float* cp = C + (size_t)row*ldc + col;
        if (accflag){ float4 o=*(const float4*)cp; v.x+=o.x; v.y+=o.y; v.z+=o.z; v.w+=o.w; }
        *(float4*)cp = v;
      }
    }
  }
}

// ---------------- hyper LSTM cell: per-row chunk_ln(4x256) + gates + ln(c) ----------------
__global__ __launch_bounds__(256) void hyper_cell(
    const float* __restrict__ lin, const float* __restrict__ c_in,
    const float* __restrict__ lnh_w, const float* __restrict__ lnh_b,
    const float* __restrict__ lnc_w, const float* __restrict__ lnc_b,
    float* __restrict__ ht_out, float* __restrict__ ct_out)
{
  int b=blockIdx.x, tid=threadIdx.x, lane=tid&63, w=tid>>6;
  __shared__ float ly[1024];
  __shared__ float red[4];
  float4 t = *(const float4*)(lin + (size_t)b*1024 + tid*4);
  float v[4]={t.x,t.y,t.z,t.w};
  // chunk = tid/64 == wave index; each wave's 64 lanes hold the 256 chunk values
  float s = wave_sum(v[0]+v[1]+v[2]+v[3]);
  float mu = s*(1.f/256.f);
  float q=0.f;
  #pragma unroll
  for (int j=0;j<4;j++){ float d=v[j]-mu; q+=d*d; }
  q = wave_sum(q);
  float rs = rsqrtf(q*(1.f/256.f)+EPSV);
  int base = tid*4;
  #pragma unroll
  for (int j=0;j<4;j++) ly[base+j] = (v[j]-mu)*rs*lnh_w[base+j]+lnh_b[base+j];
  __syncthreads();
  float ig=ly[tid], fg=ly[256+tid], og=ly[512+tid], cc=ly[768+tid];
  float co = c_in[(size_t)b*LDT + 1024 + tid];
  float cn = sigf(fg+1.f)*co + sigf(ig)*tanhf(cc);
  // LN over the 256 c values (4 waves)
  float s2 = wave_sum(cn);
  if(lane==0) red[w]=s2;
  __syncthreads();
  float mu2=(red[0]+red[1]+red[2]+red[3])*(1.f/256.f);
  __syncthreads();
  float d = cn-mu2;
  float q2 = wave_sum(d*d);
  if(lane==0) red[w]=q2;
  __syncthreads();
  float rs2 = rsqrtf((red[0]+red[1]+red[2]+red[3])*(1.f/256.f)+EPSV);
  float hh = sigf(og)*tanhf(d*rs2*lnc_w[tid]+lnc_b[tid]);
  ht_out[(size_t)b*LDT+1024+tid]=hh;
  ct_out[(size_t)b*LDT+1024+tid]=cn;
}

// ---------------- scale apply: glin = sx*Wx + sh*Wh + bh (dots over E=32 GEMM-style)
#define EST 68
__device__ __forceinline__ void stage_dot(
    const float* __restrict__ zp, const float* __restrict__ wp,
    int r0, int gc0, int g, int tid, int tx, int ty,
    float (&acc)[4][4], float* Zs, float* Ws)
{
  const int lr = tid>>2;          // 0..63
  const int le4 = (tid&3)<<2;     // 0,4,8,12
  float4 zv0 = *(const float4*)(zp + (size_t)(r0+lr)*128 + g*32 + le4);
  float4 zv1 = *(const float4*)(zp + (size_t)(r0+lr)*128 + g*32 + le4 + 16);
  float4 wv0 = *(const float4*)(wp + ((size_t)(g*1024 + gc0 + lr))*32 + le4);
  float4 wv1 = *(const float4*)(wp + ((size_t)(g*1024 + gc0 + lr))*32 + le4 + 16);
  __syncthreads();   // previous phase done reading LDS
  Zs[(le4+0)*EST+lr]=zv0.x; Zs[(le4+1)*EST+lr]=zv0.y; Zs[(le4+2)*EST+lr]=zv0.z; Zs[(le4+3)*EST+lr]=zv0.w;
  Zs[(le4+16)*EST+lr]=zv1.x; Zs[(le4+17)*EST+lr]=zv1.y; Zs[(le4+18)*EST+lr]=zv1.z; Zs[(le4+19)*EST+lr]=zv1.w;
  Ws[(le4+0)*EST+lr]=wv0.x; Ws[(le4+1)*EST+lr]=wv0.y; Ws[(le4+2)*EST+lr]=wv0.z; Ws[(le4+3)*EST+lr]=wv0.w;
  Ws[(le4+16)*EST+lr]=wv1.x; Ws[(le4+17)*EST+lr]=wv1.y; Ws[(le4+18)*EST+lr]=wv1.z; Ws[(le4+19)*EST+lr]=wv1.w;
  __syncthreads();
  #pragma unroll
  for (int i=0;i<4;i++)
    #pragma unroll
    for (int j=0;j<4;j++) acc[i][j]=0.f;
  #pragma unroll
  for (int e=0;e<32;e++){
    float4 av = *(const float4*)&Zs[e*EST + ty*4];
    float4 bv = *(const float4*)&Ws[e*EST + tx*4];
    float a[4]={av.x,av.y,av.z,av.w}, b[4]={bv.x,bv.y,bv.z,bv.w};
    #pragma unroll
    for (int i=0;i<4;i++)
      #pragma unroll
      for (int j=0;j<4;j++) acc[i][j]+=a[i]*b[j];
  }
}

__global__ __launch_bounds__(256) void scale_apply(
  const float* __restrict__ Wx, const float* __restrict__ Wh,
  const float* __restrict__ zx, const float* __restrict__ zh, const float* __restrict__ zb,
  const float* __restrict__ w1x, const float* __restrict__ w1h, const float* __restrict__ w1b,
  float* __restrict__ glin)
{
  __shared__ float Zs[32*EST], Ws[32*EST];
  int tid=threadIdx.x;
  int c0=blockIdx.x*64, r0=blockIdx.y*64;
  int g=c0>>10, gc0=c0&1023;
  int tx=tid&15, ty=tid>>4;
  float acc[4][4], gval[4][4];

  stage_dot(zx,w1x,r0,gc0,g,tid,tx,ty,acc,Zs,Ws);
  #pragma unroll
  for (int i=0;i<4;i++){
    float4 wv = *(const float4*)(Wx + (size_t)(r0+ty*4+i)*4096 + c0 + tx*4);
    gval[i][0]=acc[i][0]*wv.x; gval[i][1]=acc[i][1]*wv.y;
    gval[i][2]=acc[i][2]*wv.z; gval[i][3]=acc[i][3]*wv.w;
  }
  stage_dot(zh,w1h,r0,gc0,g,tid,tx,ty,acc,Zs,Ws);
  #pragma unroll
  for (int i=0;i<4;i++){
    float4 wv = *(const float4*)(Wh + (size_t)(r0+ty*4+i)*4096 + c0 + tx*4);
    gval[i][0]+=acc[i][0]*wv.x; gval[i][1]+=acc[i][1]*wv.y;
    gval[i][2]+=acc[i][2]*wv.z; gval[i][3]+=acc[i][3]*wv.w;
  }
  stage_dot(zb,w1b,r0,gc0,g,tid,tx,ty,acc,Zs,Ws);
  #pragma unroll
  for (int i=0;i<4;i++){
    float4 v;
    v.x=gval[i][0]+acc[i][0]; v.y=gval[i][1]+acc[i][1];
    v.z=gval[i][2]+acc[i][2]; v.w=gval[i][3]+acc[i][3];
    *(float4*)(glin + (size_t)(r0+ty*4+i)*4096 + c0 + tx*4) = v;
  }
}

// ---------------- main LSTM cell: chunk_ln(4x1024) + gates + ln(c) ----------------
__global__ __launch_bounds__(256) void main_cell(
    const float* __restrict__ glin, const float* __restrict__ c_in,
    const float* __restrict__ lnh_w, const float* __restrict__ lnh_b,
    const float* __restrict__ lnc_w, const float* __restrict__ lnc_b,
    float* __restrict__ h_out, float* __restrict__ ht_out, float* __restrict__ ct_out)
{
  int b=blockIdx.x, tid=threadIdx.x, lane=tid&63, w=tid>>6;
  __shared__ float red[16];
  float v[4][4];
  #pragma unroll
  for (int g=0;g<4;g++){
    float4 t = *(const float4*)(glin + (size_t)b*4096 + g*1024 + tid*4);
    v[g][0]=t.x; v[g][1]=t.y; v[g][2]=t.z; v[g][3]=t.w;
  }
  float mu[4], rs[4];
  #pragma unroll
  for (int g=0;g<4;g++){
    float s = wave_sum(v[g][0]+v[g][1]+v[g][2]+v[g][3]);
    if(lane==0) red[g*4+w]=s;
  }
  __syncthreads();
  #pragma unroll
  for (int g=0;g<4;g++) mu[g]=(red[g*4]+red[g*4+1]+red[g*4+2]+red[g*4+3])*(1.f/1024.f);
  __syncthreads();
  #pragma unroll
  for (int g=0;g<4;g++){
    float q=0.f;
    #pragma unroll
    for (int j=0;j<4;j++){ float d=v[g][j]-mu[g]; q+=d*d; }
    q = wave_sum(q);
    if(lane==0) red[g*4+w]=q;
  }
  __syncthreads();
  #pragma unroll
  for (int g=0;g<4;g++) rs[g]=rsqrtf((red[g*4]+red[g*4+1]+red[g*4+2]+red[g*4+3])*(1.f/1024.f)+EPSV);
  int o0=tid*4;
  float y[4][4];
  #pragma unroll
  for (int g=0;g<4;g++)
    #pragma unroll
    for (int j=0;j<4;j++){
      int idx=g*1024+o0+j;
      y[g][j]=(v[g][j]-mu[g])*rs[g]*lnh_w[idx]+lnh_b[idx];
    }
  float4 ct = *(const float4*)(c_in + (size_t)b*LDT + o0);
  float co[4]={ct.x,ct.y,ct.z,ct.w};
  float cn[4];
  #pragma unroll
  for (int j=0;j<4;j++) cn[j]=sigf(y[1][j]+1.f)*co[j] + sigf(y[0][j])*tanhf(y[3][j]);
  // LN over the 1024 c values
  float s = wave_sum(cn[0]+cn[1]+cn[2]+cn[3]);
  __syncthreads();          // red reuse guard
  if(lane==0) red[w]=s;
  __syncthreads();
  float muc=(red[0]+red[1]+red[2]+red[3])*(1.f/1024.f);
  __syncthreads();
  float q=0.f;
  #pragma unroll
  for (int j=0;j<4;j++){ float d=cn[j]-muc; q+=d*d; }
  q=wave_sum(q);
  if(lane==0) red[w]=q;
  __syncthreads();
  float rsc=rsqrtf((red[0]+red[1]+red[2]+red[3])*(1.f/1024.f)+EPSV);
  float h[4];
  #pragma unroll
  for (int j=0;j<4;j++) h[j]=sigf(y[2][j])*tanhf((cn[j]-muc)*rsc*lnc_w[o0+j]+lnc_b[o0+j]);
  float4 hv; hv.x=h[0]; hv.y=h[1]; hv.z=h[2]; hv.w=h[3];
  float4 cv; cv.x=cn[0]; cv.y=cn[1]; cv.z=cn[2]; cv.w=cn[3];
  *(float4*)(h_out +(size_t)b*1024+o0) = hv;
  *(float4*)(ht_out+(size_t)b*LDT +o0) = hv;
  *(float4*)(ct_out+(size_t)b*LDT +o0) = cv;
}

extern "C" void kernel_launch(void* const* d_in, const int* in_sizes, int n_in,
                              void* d_out, int out_size, void* d_ws, size_t ws_size,
                              hipStream_t stream) {
  (void)in_sizes; (void)n_in; (void)out_size; (void)ws_size;
  const float* x         = (const float*)d_in[0];
  const float* h_total   = (const float*)d_in[1];
  const float* c_total   = (const float*)d_in[2];
  const float* hyp_w_ih  = (const float*)d_in[3];
  const float* hyp_w_hh  = (const float*)d_in[4];
  const float* hyp_lnh_w = (const float*)d_in[5];
  const float* hyp_lnh_b = (const float*)d_in[6];
  const float* hyp_lnc_w = (const float*)d_in[7];
  const float* hyp_lnc_b = (const float*)d_in[8];
  const float* w_ih      = (const float*)d_in[9];
  const float* w_hh      = (const float*)d_in[10];
  const float* lnh_w     = (const float*)d_in[11];
  const float* lnh_b     = (const float*)d_in[12];
  const float* lnc_w     = (const float*)d_in[13];
  const float* lnc_b     = (const float*)d_in[14];
  const float* sx_w0     = (const float*)d_in[15];
  const float* sx_b0     = (const float*)d_in[16];
  const float* sx_w1     = (const float*)d_in[17];
  const float* sh_w0     = (const float*)d_in[18];
  const float* sh_b0     = (const float*)d_in[19];
  const float* sh_w1     = (const float*)d_in[20];
  const float* bh_w0     = (const float*)d_in[21];
  const float* bh_w1     = (const float*)d_in[22];

  float* out    = (float*)d_out;
  float* h_out  = out;
  float* ht_out = out + (size_t)BB*HH_MAIN;
  float* ct_out = ht_out + (size_t)BB*LDT;

  float* ws  = (float*)d_ws;
  float* lin = ws;                    // 4096*1024
  float* Wx  = lin + 4194304;         // 4096*4096
  float* Wh  = Wx  + 16777216;        // 4096*4096
  float* zx  = Wh  + 16777216;        // 4096*128
  float* zh  = zx  + 524288;
  float* zb  = zh  + 524288;

  dim3 blk(256);
  // hyper linear: lin = x@hyp_w_ih.T + h_hyper@hyp_w_hh.T
  gemm_nt<<<dim3(8,32),blk,0,stream>>>(x,512, hyp_w_ih,512, lin,1024, 512, nullptr, 0);
  gemm_nt<<<dim3(8,32),blk,0,stream>>>(h_total+1024,LDT, hyp_w_hh,256, lin,1024, 256, nullptr, 1);
  // main big GEMMs (independent of hyper path)
  gemm_nt<<<dim3(32,32),blk,0,stream>>>(x,512, w_ih,512, Wx,4096, 512, nullptr, 0);
  gemm_nt<<<dim3(32,32),blk,0,stream>>>(h_total,LDT, w_hh,1024, Wh,4096, 1024, nullptr, 0);
  // hyper cell -> writes h_hyper/c_hyper into the output h_total/c_total sections
  hyper_cell<<<4096,blk,0,stream>>>(lin, c_total, hyp_lnh_w, hyp_lnh_b, hyp_lnc_w, hyp_lnc_b, ht_out, ct_out);
  // z projections: z = h_hyper @ w0.T (+ b0)   (N=128, K=256)
  gemm_nt<<<dim3(1,32),blk,0,stream>>>(ht_out+1024,LDT, sx_w0,256, zx,128, 256, sx_b0, 0);
  gemm_nt<<<dim3(1,32),blk,0,stream>>>(ht_out+1024,LDT, sh_w0,256, zh,128, 256, sh_b0, 0);
  gemm_nt<<<dim3(1,32),blk,0,stream>>>(ht_out+1024,LDT, bh_w0,256, zb,128, 256, nullptr, 0);
  // glin = scale_x*Wx + scale_h*Wh + bias_h   (writes in place over Wx)
  scale_apply<<<dim3(64,64),blk,0,stream>>>(Wx, Wh, zx, zh, zb, sx_w1, sh_w1, bh_w1, Wx);
  // main cell
  main_cell<<<4096,blk,0,stream>>>(Wx, c_total, lnh_w, lnh_b, lnc_w, lnc_b, h_out, ht_out, ct_out);
}

// Round 3
// 711.099 us; speedup vs baseline: 1.4868x; 1.4868x over previous
//
#include <hip/hip_runtime.h>
#include <math.h>

typedef unsigned short u16;
typedef unsigned int u32;
typedef unsigned long long u64;
typedef __attribute__((ext_vector_type(4))) float vf4;
typedef __attribute__((ext_vector_type(8))) short s16x8;

#define EPSV 1e-5f
#define BB 4096
#define LDT 1280   // H + HH

__device__ __forceinline__ float sigf(float x){
  float e = expf(-fabsf(x));
  float r = 1.f/(1.f+e);
  return x>=0.f ? r : 1.f-r;
}

__device__ __forceinline__ float wave_sum(float v){
  #pragma unroll
  for (int m=32;m>0;m>>=1) v += __shfl_xor(v, m);
  return v;
}

__device__ __forceinline__ u16 f2bf(float f){
  u32 u = __builtin_bit_cast(u32, f);
  u32 r = u + 0x7FFFu + ((u>>16)&1u);
  return (u16)(r>>16);
}
__device__ __forceinline__ float bf2f(u16 h){
  u32 u = ((u32)h)<<16;
  return __builtin_bit_cast(float, u);
}

#define AS1 __attribute__((address_space(1)))
#define AS3 __attribute__((address_space(3)))
__device__ __forceinline__ void gload_lds16(const u16* g, u16* l){
  __builtin_amdgcn_global_load_lds((const AS1 void*)g, (AS3 void*)l, 16, 0, 0);
}

// ---------------- split conversion (Markidis 3-term, ASYMMETRIC layouts) ----------------
// mode 0 (A side / activations): out row = [ hi | lo | hi ]
// mode 1 (B side / weights):     out row = [ hi | hi | lo ]
// => NT GEMM over K'=3K computes Ahi*Bhi + Alo*Bhi + Ahi*Blo  (~fp32 accuracy)
__global__ __launch_bounds__(64) void cvt_split(const float* __restrict__ in, int ld_in, int K,
                                                u16* __restrict__ out, int ld_out, int mode)
{
  int row = blockIdx.y;
  int c4 = (blockIdx.x*64 + threadIdx.x)*4;
  if (c4 >= K) return;
  float4 v = *(const float4*)(in + (size_t)row*ld_in + c4);
  float vv[4] = {v.x, v.y, v.z, v.w};
  u64 hi=0, lo=0;
  #pragma unroll
  for (int j=0;j<4;j++){
    u16 h = f2bf(vv[j]);
    u16 l = f2bf(vv[j] - bf2f(h));
    hi |= (u64)h << (16*j);
    lo |= (u64)l << (16*j);
  }
  u16* o = out + (size_t)row*ld_out + c4;
  *(u64*)(o) = hi;
  if (mode == 0){
    *(u64*)(o + K)   = lo;
    *(u64*)(o + 2*K) = hi;
  } else {
    *(u64*)(o + K)   = hi;
    *(u64*)(o + 2*K) = lo;
  }
}

// ---------------- bf16 MFMA NT GEMM: C[m,n] = sum_k A[m,k]*B[n,k]  (fp32 out) -----------
// 128x128 tile, BK=32, 256 threads (4 waves 2x2), global_load_lds width-16 staging,
// linear LDS dest + inverse-swizzled global source + swizzled ds_read (rule 21).
__global__ __launch_bounds__(256) void gemm_bf16nt(
    const u16* __restrict__ A, int lda,
    const u16* __restrict__ B, int ldb,
    float* __restrict__ C, int ldc,
    int K, int accflag)
{
  __shared__ u16 As[128*32];
  __shared__ u16 Bs[128*32];
  const int tid = threadIdx.x;
  const int lane = tid & 63;
  const int w = tid >> 6;
  const int wr = w >> 1, wc = w & 1;
  const int m0 = blockIdx.y*128, n0 = blockIdx.x*128;

  vf4 acc[4][4];
  #pragma unroll
  for (int i=0;i<4;i++)
    #pragma unroll
    for (int j=0;j<4;j++) acc[i][j] = (vf4){0.f,0.f,0.f,0.f};

  // staging: wave w covers 16B-chunks [w*128,(w+1)*128) of each tile, 2 issues of 64.
  // chunk c -> LDS physical (row=c>>2, slot=c&3); physical slot p holds logical
  // slot p ^ ((row>>1)&3)  (inverse-swizzled source address).
  const int c0i = w*128 + lane;
  const int c1i = c0i + 64;
  const int r0i = c0i>>2, s0i = (c0i&3) ^ ((r0i>>1)&3);
  const int r1i = c1i>>2, s1i = (c1i&3) ^ ((r1i>>1)&3);
  const u16* gA0 = A + (size_t)(m0+r0i)*lda + s0i*8;
  const u16* gA1 = A + (size_t)(m0+r1i)*lda + s1i*8;
  const u16* gB0 = B + (size_t)(n0+r0i)*ldb + s0i*8;
  const u16* gB1 = B + (size_t)(n0+r1i)*ldb + s1i*8;
  u16* lA0 = As + w*1024;
  u16* lA1 = As + w*1024 + 512;
  u16* lB0 = Bs + w*1024;
  u16* lB1 = Bs + w*1024 + 512;

  const int kg = lane>>4, lm = lane&15;

  for (int k0=0; k0<K; k0+=32){
    __syncthreads();
    gload_lds16(gA0 + k0, lA0);
    gload_lds16(gA1 + k0, lA1);
    gload_lds16(gB0 + k0, lB0);
    gload_lds16(gB1 + k0, lB1);
    __syncthreads();
    s16x8 af[4], bfr[4];
    #pragma unroll
    for (int i=0;i<4;i++){
      int ra = wr*64 + i*16 + lm;
      int sa = kg ^ ((ra>>1)&3);
      af[i] = *(const s16x8*)(As + ra*32 + sa*8);
      int rb = wc*64 + i*16 + lm;
      int sb = kg ^ ((rb>>1)&3);
      bfr[i] = *(const s16x8*)(Bs + rb*32 + sb*8);
    }
    #pragma unroll
    for (int i=0;i<4;i++)
      #pragma unroll
      for (int j=0;j<4;j++)
        acc[i][j] = __builtin_amdgcn_mfma_f32_16x16x32_bf16(af[i], bfr[j], acc[i][j], 0, 0, 0);
  }

  // C/D layout (m89-verified): col = lane&15, row = (lane>>4)*4 + reg
  const int lhi = lane>>4;
  #pragma unroll
  for (int i=0;i<4;i++){
    int rbase = m0 + wr*64 + i*16 + lhi*4;
    #pragma unroll
    for (int j=0;j<4;j++){
      int cc = n0 + wc*64 + j*16 + lm;
      #pragma unroll
      for (int r=0;r<4;r++){
        float v = acc[i][j][r];
        float* pC = C + (size_t)(rbase+r)*ldc + cc;
        if (accflag) v += *pC;
        *pC = v;
      }
    }
  }
}

// ---------------- fp32 GEMM (NT) for small z projections -------------------------------
#define TK 16
#define ALD 132
__global__ __launch_bounds__(256) void gemm_nt(
    const float* __restrict__ A, int lda,
    const float* __restrict__ Bm, int ldb,
    float* __restrict__ C, int ldc,
    int K, const float* __restrict__ bias, int accflag)
{
  __shared__ float Asf[TK*ALD];
  __shared__ float Bsf[TK*ALD];
  const int tid = threadIdx.x;
  const int m0 = blockIdx.y*128, n0 = blockIdx.x*128;
  const int ar = tid>>2;
  const int ak = (tid&3)<<2;
  const int tx = tid&15, ty = tid>>4;
  float acc[8][8];
  #pragma unroll
  for (int i=0;i<8;i++)
    #pragma unroll
    for (int j=0;j<8;j++) acc[i][j]=0.f;

  const float* Ap0 = A + (size_t)(m0+ar)*lda + ak;
  const float* Ap1 = A + (size_t)(m0+ar+64)*lda + ak;
  const float* Bp0 = Bm + (size_t)(n0+ar)*ldb + ak;
  const float* Bp1 = Bm + (size_t)(n0+ar+64)*ldb + ak;

  for (int k0=0;k0<K;k0+=TK){
    float4 a0 = *(const float4*)(Ap0 + k0);
    float4 a1 = *(const float4*)(Ap1 + k0);
    float4 b0 = *(const float4*)(Bp0 + k0);
    float4 b1 = *(const float4*)(Bp1 + k0);
    __syncthreads();
    Asf[(ak+0)*ALD+ar]=a0.x; Asf[(ak+1)*ALD+ar]=a0.y; Asf[(ak+2)*ALD+ar]=a0.z; Asf[(ak+3)*ALD+ar]=a0.w;
    Asf[(ak+0)*ALD+ar+64]=a1.x; Asf[(ak+1)*ALD+ar+64]=a1.y; Asf[(ak+2)*ALD+ar+64]=a1.z; Asf[(ak+3)*ALD+ar+64]=a1.w;
    Bsf[(ak+0)*ALD+ar]=b0.x; Bsf[(ak+1)*ALD+ar]=b0.y; Bsf[(ak+2)*ALD+ar]=b0.z; Bsf[(ak+3)*ALD+ar]=b0.w;
    Bsf[(ak+0)*ALD+ar+64]=b1.x; Bsf[(ak+1)*ALD+ar+64]=b1.y; Bsf[(ak+2)*ALD+ar+64]=b1.z; Bsf[(ak+3)*ALD+ar+64]=b1.w;
    __syncthreads();
    #pragma unroll
    for (int kk=0;kk<TK;kk++){
      float4 av0 = *(const float4*)&Asf[kk*ALD + ty*4];
      float4 av1 = *(const float4*)&Asf[kk*ALD + ty*4 + 64];
      float4 bv0 = *(const float4*)&Bsf[kk*ALD + tx*4];
      float4 bv1 = *(const float4*)&Bsf[kk*ALD + tx*4 + 64];
      float a[8]={av0.x,av0.y,av0.z,av0.w,av1.x,av1.y,av1.z,av1.w};
      float b[8]={bv0.x,bv0.y,bv0.z,bv0.w,bv1.x,bv1.y,bv1.z,bv1.w};
      #pragma unroll
      for (int i=0;i<8;i++)
        #pragma unroll
        for (int j=0;j<8;j++) acc[i][j] += a[i]*b[j];
    }
  }
  #pragma unroll
  for (int ig=0;ig<2;ig++){
    #pragma unroll
    for (int i=0;i<4;i++){
      int row = m0 + ig*64 + ty*4 + i;
      #pragma unroll
      for (int jg=0;jg<2;jg++){
        int col = n0 + jg*64 + tx*4;
        float4 v;
        v.x=acc[ig*4+i][jg*4+0]; v.y=acc[ig*4+i][jg*4+1];
        v.z=acc[ig*4+i][jg*4+2]; v.w=acc[ig*4+i][jg*4+3];
        if (bias){ v.x+=bias[col]; v.y+=bias[col+1]; v.z+=bias[col+2]; v.w+=bias[col+3]; }
        float* cp = C + (size_t)row*ldc + col;
        if (accflag){ float4 o=*(const float4*)cp; v.x+=o.x; v.y+=o.y; v.z+=o.z; v.w+=o.w; }
        *(float4*)cp = v;
      }
    }
  }
}

// ---------------- hyper LSTM cell ----------------
__global__ __launch_bounds__(256) void hyper_cell(
    const float* __restrict__ lin, const float* __restrict__ c_in,
    const float* __restrict__ lnh_w, const float* __restrict__ lnh_b,
    const float* __restrict__ lnc_w, const float* __restrict__ lnc_b,
    float* __restrict__ ht_out, float* __restrict__ ct_out)
{
  int b=blockIdx.x, tid=threadIdx.x, lane=tid&63, w=tid>>6;
  __shared__ float ly[1024];
  __shared__ float red[4];
  float4 t = *(const float4*)(lin + (size_t)b*1024 + tid*4);
  float v[4]={t.x,t.y,t.z,t.w};
  float s = wave_sum(v[0]+v[1]+v[2]+v[3]);
  float mu = s*(1.f/256.f);
  float q=0.f;
  #pragma unroll
  for (int j=0;j<4;j++){ float d=v[j]-mu; q+=d*d; }
  q = wave_sum(q);
  float rs = rsqrtf(q*(1.f/256.f)+EPSV);
  int base = tid*4;
  #pragma unroll
  for (int j=0;j<4;j++) ly[base+j] = (v[j]-mu)*rs*lnh_w[base+j]+lnh_b[base+j];
  __syncthreads();
  float ig=ly[tid], fg=ly[256+tid], og=ly[512+tid], cc=ly[768+tid];
  float co = c_in[(size_t)b*LDT + 1024 + tid];
  float cn = sigf(fg+1.f)*co + sigf(ig)*tanhf(cc);
  float s2 = wave_sum(cn);
  if(lane==0) red[w]=s2;
  __syncthreads();
  float mu2=(red[0]+red[1]+red[2]+red[3])*(1.f/256.f);
  __syncthreads();
  float d = cn-mu2;
  float q2 = wave_sum(d*d);
  if(lane==0) red[w]=q2;
  __syncthreads();
  float rs2 = rsqrtf((red[0]+red[1]+red[2]+red[3])*(1.f/256.f)+EPSV);
  float hh = sigf(og)*tanhf(d*rs2*lnc_w[tid]+lnc_b[tid]);
  ht_out[(size_t)b*LDT+1024+tid]=hh;
  ct_out[(size_t)b*LDT+1024+tid]=cn;
}

// ---------------- scale apply ----------------
#define EST 68
__device__ __forceinline__ void stage_dot(
    const float* __restrict__ zp, const float* __restrict__ wp,
    int r0, int gc0, int g, int tid, int tx, int ty,
    float (&acc)[4][4], float* Zs, float* Ws)
{
  const int lr = tid>>2;
  const int le4 = (tid&3)<<2;
  float4 zv0 = *(const float4*)(zp + (size_t)(r0+lr)*128 + g*32 + le4);
  float4 zv1 = *(const float4*)(zp + (size_t)(r0+lr)*128 + g*32 + le4 + 16);
  float4 wv0 = *(const float4*)(wp + ((size_t)(g*1024 + gc0 + lr))*32 + le4);
  float4 wv1 = *(const float4*)(wp + ((size_t)(g*1024 + gc0 + lr))*32 + le4 + 16);
  __syncthreads();
  Zs[(le4+0)*EST+lr]=zv0.x; Zs[(le4+1)*EST+lr]=zv0.y; Zs[(le4+2)*EST+lr]=zv0.z; Zs[(le4+3)*EST+lr]=zv0.w;
  Zs[(le4+16)*EST+lr]=zv1.x; Zs[(le4+17)*EST+lr]=zv1.y; Zs[(le4+18)*EST+lr]=zv1.z; Zs[(le4+19)*EST+lr]=zv1.w;
  Ws[(le4+0)*EST+lr]=wv0.x; Ws[(le4+1)*EST+lr]=wv0.y; Ws[(le4+2)*EST+lr]=wv0.z; Ws[(le4+3)*EST+lr]=wv0.w;
  Ws[(le4+16)*EST+lr]=wv1.x; Ws[(le4+17)*EST+lr]=wv1.y; Ws[(le4+18)*EST+lr]=wv1.z; Ws[(le4+19)*EST+lr]=wv1.w;
  __syncthreads();
  #pragma unroll
  for (int i=0;i<4;i++)
    #pragma unroll
    for (int j=0;j<4;j++) acc[i][j]=0.f;
  #pragma unroll
  for (int e=0;e<32;e++){
    float4 av = *(const float4*)&Zs[e*EST + ty*4];
    float4 bv = *(const float4*)&Ws[e*EST + tx*4];
    float a[4]={av.x,av.y,av.z,av.w}, b[4]={bv.x,bv.y,bv.z,bv.w};
    #pragma unroll
    for (int i=0;i<4;i++)
      #pragma unroll
      for (int j=0;j<4;j++) acc[i][j]+=a[i]*b[j];
  }
}

__global__ __launch_bounds__(256) void scale_apply(
  const float* __restrict__ Wx, const float* __restrict__ Wh,
  const float* __restrict__ zx, const float* __restrict__ zh, const float* __restrict__ zb,
  const float* __restrict__ w1x, const float* __restrict__ w1h, const float* __restrict__ w1b,
  float* __restrict__ glin)
{
  __shared__ float Zs[32*EST], Ws[32*EST];
  int tid=threadIdx.x;
  int c0=blockIdx.x*64, r0=blockIdx.y*64;
  int g=c0>>10, gc0=c0&1023;
  int tx=tid&15, ty=tid>>4;
  float acc[4][4], gval[4][4];

  stage_dot(zx,w1x,r0,gc0,g,tid,tx,ty,acc,Zs,Ws);
  #pragma unroll
  for (int i=0;i<4;i++){
    float4 wv = *(const float4*)(Wx + (size_t)(r0+ty*4+i)*4096 + c0 + tx*4);
    gval[i][0]=acc[i][0]*wv.x; gval[i][1]=acc[i][1]*wv.y;
    gval[i][2]=acc[i][2]*wv.z; gval[i][3]=acc[i][3]*wv.w;
  }
  stage_dot(zh,w1h,r0,gc0,g,tid,tx,ty,acc,Zs,Ws);
  #pragma unroll
  for (int i=0;i<4;i++){
    float4 wv = *(const float4*)(Wh + (size_t)(r0+ty*4+i)*4096 + c0 + tx*4);
    gval[i][0]+=acc[i][0]*wv.x; gval[i][1]+=acc[i][1]*wv.y;
    gval[i][2]+=acc[i][2]*wv.z; gval[i][3]+=acc[i][3]*wv.w;
  }
  stage_dot(zb,w1b,r0,gc0,g,tid,tx,ty,acc,Zs,Ws);
  #pragma unroll
  for (int i=0;i<4;i++){
    float4 v;
    v.x=gval[i][0]+acc[i][0]; v.y=gval[i][1]+acc[i][1];
    v.z=gval[i][2]+acc[i][2]; v.w=gval[i][3]+acc[i][3];
    *(float4*)(glin + (size_t)(r0+ty*4+i)*4096 + c0 + tx*4) = v;
  }
}

// ---------------- main LSTM cell ----------------
__global__ __launch_bounds__(256) void main_cell(
    const float* __restrict__ glin, const float* __restrict__ c_in,
    const float* __restrict__ lnh_w, const float* __restrict__ lnh_b,
    const float* __restrict__ lnc_w, const float* __restrict__ lnc_b,
    float* __restrict__ h_out, float* __restrict__ ht_out, float* __restrict__ ct_out)
{
  int b=blockIdx.x, tid=threadIdx.x, lane=tid&63, w=tid>>6;
  __shared__ float red[16];
  float v[4][4];
  #pragma unroll
  for (int g=0;g<4;g++){
    float4 t = *(const float4*)(glin + (size_t)b*4096 + g*1024 + tid*4);
    v[g][0]=t.x; v[g][1]=t.y; v[g][2]=t.z; v[g][3]=t.w;
  }
  float mu[4], rs[4];
  #pragma unroll
  for (int g=0;g<4;g++){
    float s = wave_sum(v[g][0]+v[g][1]+v[g][2]+v[g][3]);
    if(lane==0) red[g*4+w]=s;
  }
  __syncthreads();
  #pragma unroll
  for (int g=0;g<4;g++) mu[g]=(red[g*4]+red[g*4+1]+red[g*4+2]+red[g*4+3])*(1.f/1024.f);
  __syncthreads();
  #pragma unroll
  for (int g=0;g<4;g++){
    float q=0.f;
    #pragma unroll
    for (int j=0;j<4;j++){ float d=v[g][j]-mu[g]; q+=d*d; }
    q = wave_sum(q);
    if(lane==0) red[g*4+w]=q;
  }
  __syncthreads();
  #pragma unroll
  for (int g=0;g<4;g++) rs[g]=rsqrtf((red[g*4]+red[g*4+1]+red[g*4+2]+red[g*4+3])*(1.f/1024.f)+EPSV);
  int o0=tid*4;
  float y[4][4];
  #pragma unroll
  for (int g=0;g<4;g++)
    #pragma unroll
    for (int j=0;j<4;j++){
      int idx=g*1024+o0+j;
      y[g][j]=(v[g][j]-mu[g])*rs[g]*lnh_w[idx]+lnh_b[idx];
    }
  float4 ct = *(const float4*)(c_in + (size_t)b*LDT + o0);
  float co[4]={ct.x,ct.y,ct.z,ct.w};
  float cn[4];
  #pragma unroll
  for (int j=0;j<4;j++) cn[j]=sigf(y[1][j]+1.f)*co[j] + sigf(y[0][j])*tanhf(y[3][j]);
  float s = wave_sum(cn[0]+cn[1]+cn[2]+cn[3]);
  __syncthreads();
  if(lane==0) red[w]=s;
  __syncthreads();
  float muc=(red[0]+red[1]+red[2]+red[3])*(1.f/1024.f);
  __syncthreads();
  float q=0.f;
  #pragma unroll
  for (int j=0;j<4;j++){ float d=cn[j]-muc; q+=d*d; }
  q=wave_sum(q);
  if(lane==0) red[w]=q;
  __syncthreads();
  float rsc=rsqrtf((red[0]+red[1]+red[2]+red[3])*(1.f/1024.f)+EPSV);
  float h[4];
  #pragma unroll
  for (int j=0;j<4;j++) h[j]=sigf(y[2][j])*tanhf((cn[j]-muc)*rsc*lnc_w[o0+j]+lnc_b[o0+j]);
  float4 hv; hv.x=h[0]; hv.y=h[1]; hv.z=h[2]; hv.w=h[3];
  float4 cv; cv.x=cn[0]; cv.y=cn[1]; cv.z=cn[2]; cv.w=cn[3];
  *(float4*)(h_out +(size_t)b*1024+o0) = hv;
  *(float4*)(ht_out+(size_t)b*LDT +o0) = hv;
  *(float4*)(ct_out+(size_t)b*LDT +o0) = cv;
}

extern "C" void kernel_launch(void* const* d_in, const int* in_sizes, int n_in,
                              void* d_out, int out_size, void* d_ws, size_t ws_size,
                              hipStream_t stream) {
  (void)in_sizes; (void)n_in; (void)out_size; (void)ws_size;
  const float* x         = (const float*)d_in[0];
  const float* h_total   = (const float*)d_in[1];
  const float* c_total   = (const float*)d_in[2];
  const float* hyp_w_ih  = (const float*)d_in[3];
  const float* hyp_w_hh  = (const float*)d_in[4];
  const float* hyp_lnh_w = (const float*)d_in[5];
  const float* hyp_lnh_b = (const float*)d_in[6];
  const float* hyp_lnc_w = (const float*)d_in[7];
  const float* hyp_lnc_b = (const float*)d_in[8];
  const float* w_ih      = (const float*)d_in[9];
  const float* w_hh      = (const float*)d_in[10];
  const float* lnh_w     = (const float*)d_in[11];
  const float* lnh_b     = (const float*)d_in[12];
  const float* lnc_w     = (const float*)d_in[13];
  const float* lnc_b     = (const float*)d_in[14];
  const float* sx_w0     = (const float*)d_in[15];
  const float* sx_b0     = (const float*)d_in[16];
  const float* sx_w1     = (const float*)d_in[17];
  const float* sh_w0     = (const float*)d_in[18];
  const float* sh_b0     = (const float*)d_in[19];
  const float* sh_w1     = (const float*)d_in[20];
  const float* bh_w0     = (const float*)d_in[21];
  const float* bh_w1     = (const float*)d_in[22];

  float* out    = (float*)d_out;
  float* h_out  = out;
  float* ht_out = out + (size_t)BB*1024;
  float* ct_out = ht_out + (size_t)BB*LDT;

  char* p = (char*)d_ws;
  float* lin = (float*)p;  p += (size_t)4096*1024*4;
  float* Wx  = (float*)p;  p += (size_t)4096*4096*4;
  float* Wh  = (float*)p;  p += (size_t)4096*4096*4;
  float* zx  = (float*)p;  p += (size_t)4096*128*4;
  float* zh  = (float*)p;  p += (size_t)4096*128*4;
  float* zb  = (float*)p;  p += (size_t)4096*128*4;
  u16* Xbig   = (u16*)p;   p += (size_t)4096*1536*2;
  u16* Hbig   = (u16*)p;   p += (size_t)4096*3072*2;
  u16* Wihb   = (u16*)p;   p += (size_t)4096*1536*2;
  u16* Whhb   = (u16*)p;   p += (size_t)4096*3072*2;
  u16* Hhypb  = (u16*)p;   p += (size_t)4096*768*2;
  u16* Wihhyp = (u16*)p;   p += (size_t)1024*1536*2;
  u16* Whhhyp = (u16*)p;   p += (size_t)1024*768*2;

  // split-bf16 conversions (mode 0 = activations [hi|lo|hi], mode 1 = weights [hi|hi|lo])
  cvt_split<<<dim3(2,4096),64,0,stream>>>(x, 512, 512, Xbig, 1536, 0);
  cvt_split<<<dim3(4,4096),64,0,stream>>>(h_total, LDT, 1024, Hbig, 3072, 0);
  cvt_split<<<dim3(1,4096),64,0,stream>>>(h_total+1024, LDT, 256, Hhypb, 768, 0);
  cvt_split<<<dim3(2,4096),64,0,stream>>>(w_ih, 512, 512, Wihb, 1536, 1);
  cvt_split<<<dim3(4,4096),64,0,stream>>>(w_hh, 1024, 1024, Whhb, 3072, 1);
  cvt_split<<<dim3(2,1024),64,0,stream>>>(hyp_w_ih, 512, 512, Wihhyp, 1536, 1);
  cvt_split<<<dim3(1,1024),64,0,stream>>>(hyp_w_hh, 256, 256, Whhhyp, 768, 1);

  // hyper linear: lin = x@hyp_w_ih.T + h_hyper@hyp_w_hh.T   (split-bf16 MFMA)
  gemm_bf16nt<<<dim3(8,32),256,0,stream>>>(Xbig,1536, Wihhyp,1536, lin,1024, 1536, 0);
  gemm_bf16nt<<<dim3(8,32),256,0,stream>>>(Hhypb,768, Whhhyp,768, lin,1024, 768, 1);
  // main big GEMMs
  gemm_bf16nt<<<dim3(32,32),256,0,stream>>>(Xbig,1536, Wihb,1536, Wx,4096, 1536, 0);
  gemm_bf16nt<<<dim3(32,32),256,0,stream>>>(Hbig,3072, Whhb,3072, Wh,4096, 3072, 0);

  hyper_cell<<<4096,256,0,stream>>>(lin, c_total, hyp_lnh_w, hyp_lnh_b, hyp_lnc_w, hyp_lnc_b, ht_out, ct_out);

  gemm_nt<<<dim3(1,32),256,0,stream>>>(ht_out+1024,LDT, sx_w0,256, zx,128, 256, sx_b0, 0);
  gemm_nt<<<dim3(1,32),256,0,stream>>>(ht_out+1024,LDT, sh_w0,256, zh,128, 256, sh_b0, 0);
  gemm_nt<<<dim3(1,32),256,0,stream>>>(ht_out+1024,LDT, bh_w0,256, zb,128, 256, nullptr, 0);

  scale_apply<<<dim3(64,64),256,0,stream>>>(Wx, Wh, zx, zh, zb, sx_w1, sh_w1, bh_w1, Wx);
  main_cell<<<4096,256,0,stream>>>(Wx, c_total, lnh_w, lnh_b, lnc_w, lnc_b, h_out, ht_out, ct_out);
}

// Round 4
// 561.987 us; speedup vs baseline: 1.8813x; 1.2653x over previous
//
#include <hip/hip_runtime.h>
#include <math.h>

typedef unsigned short u16;
typedef unsigned int u32;
typedef unsigned long long u64;
typedef __attribute__((ext_vector_type(4))) float vf4;
typedef __attribute__((ext_vector_type(8))) short s16x8;

#define EPSV 1e-5f
#define BB 4096
#define LDT 1280   // H + HH

__device__ __forceinline__ float sigf(float x){
  float e = expf(-fabsf(x));
  float r = 1.f/(1.f+e);
  return x>=0.f ? r : 1.f-r;
}

__device__ __forceinline__ float wave_sum(float v){
  #pragma unroll
  for (int m=32;m>0;m>>=1) v += __shfl_xor(v, m);
  return v;
}

__device__ __forceinline__ u16 f2bf(float f){
  u32 u = __builtin_bit_cast(u32, f);
  u32 r = u + 0x7FFFu + ((u>>16)&1u);
  return (u16)(r>>16);
}
__device__ __forceinline__ float bf2f(u16 h){
  u32 u = ((u32)h)<<16;
  return __builtin_bit_cast(float, u);
}

#define AS1 __attribute__((address_space(1)))
#define AS3 __attribute__((address_space(3)))
__device__ __forceinline__ void gload_lds16(const u16* g, u16* l){
  __builtin_amdgcn_global_load_lds((const AS1 void*)g, (AS3 void*)l, 16, 0, 0);
}

// ---------------- split conversion (Markidis 3-term, ASYMMETRIC layouts) ----------------
// mode 0 (A side / activations): out row = [ hi | lo | hi ]
// mode 1 (B side / weights):     out row = [ hi | hi | lo ]
__global__ __launch_bounds__(64) void cvt_split(const float* __restrict__ in, int ld_in, int K,
                                                u16* __restrict__ out, int ld_out, int mode)
{
  int row = blockIdx.y;
  int c4 = (blockIdx.x*64 + threadIdx.x)*4;
  if (c4 >= K) return;
  float4 v = *(const float4*)(in + (size_t)row*ld_in + c4);
  float vv[4] = {v.x, v.y, v.z, v.w};
  u64 hi=0, lo=0;
  #pragma unroll
  for (int j=0;j<4;j++){
    u16 h = f2bf(vv[j]);
    u16 l = f2bf(vv[j] - bf2f(h));
    hi |= (u64)h << (16*j);
    lo |= (u64)l << (16*j);
  }
  u16* o = out + (size_t)row*ld_out + c4;
  *(u64*)(o) = hi;
  if (mode == 0){
    *(u64*)(o + K)   = lo;
    *(u64*)(o + 2*K) = hi;
  } else {
    *(u64*)(o + K)   = hi;
    *(u64*)(o + 2*K) = lo;
  }
}

// ================= 256x256 8-phase bf16 MFMA NT GEMM (T2+T3+T4+T5) =================
// 512 threads = 8 waves (2M x 4N), BK=64, double-buffered 128KiB LDS.
// Swizzle: LDS[row][slot16] holds global (row, slot16 ^ (row&7)); ds_read applies same XOR.
template<int P>
__device__ __forceinline__ void load_afrag(const u16* Ab, int wm, int lm, int kg, s16x8 af[2][2]){
  #pragma unroll
  for (int fl=0; fl<2; fl++)
    #pragma unroll
    for (int kk=0; kk<2; kk++){
      int row = wm*128 + (P*2+fl)*16 + lm;
      int sl = (kk*4+kg) ^ (row&7);
      af[fl][kk] = *(const s16x8*)(Ab + row*64 + sl*8);
    }
}

template<int P>
__device__ __forceinline__ void mfma_phase(vf4 acc[8][4], const s16x8 af[2][2], const s16x8 bf[4][2]){
  __builtin_amdgcn_s_setprio(1);
  #pragma unroll
  for (int fl=0; fl<2; fl++)
    #pragma unroll
    for (int j=0; j<4; j++)
      #pragma unroll
      for (int kk=0; kk<2; kk++)
        acc[P*2+fl][j] = __builtin_amdgcn_mfma_f32_16x16x32_bf16(af[fl][kk], bf[j][kk], acc[P*2+fl][j], 0, 0, 0);
  __builtin_amdgcn_s_setprio(0);
}

__global__ __launch_bounds__(512, 2) void gemm256(
    const u16* __restrict__ A, int lda,
    const u16* __restrict__ B, int ldb,
    float* __restrict__ C, int ldc, int K)
{
  __shared__ u16 As[2][256*64];
  __shared__ u16 Bs[2][256*64];
  const int tid = threadIdx.x;
  const int lane = tid & 63;
  const int wid = tid >> 6;
  const int wm = wid >> 2, wn = wid & 3;
  const int m0 = blockIdx.y*256, n0 = blockIdx.x*256;
  const int kg = lane>>4, lm = lane&15;

  vf4 acc[8][4];
  #pragma unroll
  for (int i=0;i<8;i++)
    #pragma unroll
    for (int j=0;j<4;j++) acc[i][j] = (vf4){0.f,0.f,0.f,0.f};

  // staging map: 2048 16B-chunks per matrix per K-tile; thread covers chunk q*512+tid.
  // chunk c: row=c>>3, phys slot=c&7; source col16 = slot ^ (row&7) (inverse swizzle).
  const u16* gA[4]; const u16* gB[4]; int ldsOff[4];
  #pragma unroll
  for (int q=0;q<4;q++){
    int c = q*512 + tid;
    int row = c>>3, slot = c&7;
    int scol = slot ^ (row&7);
    gA[q] = A + (size_t)(m0+row)*lda + scol*8;
    gB[q] = B + (size_t)(n0+row)*ldb + scol*8;
    ldsOff[q] = (q*512 + wid*64)*8;   // wave-uniform dest base (lane*16B appended by HW)
  }

  const int NT = K>>6;
  // prologue: stage tile 0 into buf 0 (8 loads/thread)
  #pragma unroll
  for (int q=0;q<4;q++) gload_lds16(gA[q], &As[0][ldsOff[q]]);
  #pragma unroll
  for (int q=0;q<4;q++) gload_lds16(gB[q], &Bs[0][ldsOff[q]]);

  for (int t=0; t<NT; ++t){
    const int cur = t&1, nxt = cur^1;
    const u16* Ab = As[cur];
    const u16* Bb = Bs[cur];
    // ---- phase 0: stage next A, counted wait, B-frags + A m0-1, 16 MFMA
    if (t+1 < NT){
      const int kb = (t+1)<<6;
      #pragma unroll
      for (int q=0;q<4;q++) gload_lds16(gA[q]+kb, &As[nxt][ldsOff[q]]);
      __builtin_amdgcn_sched_barrier(0);
      asm volatile("s_waitcnt vmcnt(4)" ::: "memory");   // tile t's 8 landed; 4 newest fly
    } else {
      asm volatile("s_waitcnt vmcnt(0)" ::: "memory");
    }
    __builtin_amdgcn_sched_barrier(0);
    __builtin_amdgcn_s_barrier();

    s16x8 bfrag[4][2];
    #pragma unroll
    for (int j=0;j<4;j++)
      #pragma unroll
      for (int kk=0;kk<2;kk++){
        int row = wn*64 + j*16 + lm;
        int sl = (kk*4+kg) ^ (row&7);
        bfrag[j][kk] = *(const s16x8*)(Bb + row*64 + sl*8);
      }
    s16x8 af[2][2];
    load_afrag<0>(Ab, wm, lm, kg, af);
    mfma_phase<0>(acc, af, bfrag);
    __builtin_amdgcn_s_barrier();

    // ---- phase 1: stage next B, A m2-3
    if (t+1 < NT){
      const int kb = (t+1)<<6;
      #pragma unroll
      for (int q=0;q<4;q++) gload_lds16(gB[q]+kb, &Bs[nxt][ldsOff[q]]);
    }
    load_afrag<1>(Ab, wm, lm, kg, af);
    mfma_phase<1>(acc, af, bfrag);
    __builtin_amdgcn_s_barrier();

    // ---- phase 2
    load_afrag<2>(Ab, wm, lm, kg, af);
    mfma_phase<2>(acc, af, bfrag);
    __builtin_amdgcn_s_barrier();

    // ---- phase 3
    load_afrag<3>(Ab, wm, lm, kg, af);
    mfma_phase<3>(acc, af, bfrag);
    __builtin_amdgcn_s_barrier();
  }

  // C/D layout (m89-verified): col = lane&15, row = (lane>>4)*4 + reg
  #pragma unroll
  for (int f=0; f<8; f++){
    int rb = m0 + wm*128 + f*16 + kg*4;
    #pragma unroll
    for (int j=0; j<4; j++){
      int cc = n0 + wn*64 + j*16 + lm;
      #pragma unroll
      for (int r=0; r<4; r++)
        C[(size_t)(rb+r)*ldc + cc] = acc[f][j][r];
    }
  }
}

// ---------------- 128x128 bf16 MFMA NT GEMM (m97 structure) — hyper path ----------------
__global__ __launch_bounds__(256) void gemm_bf16nt(
    const u16* __restrict__ A, int lda,
    const u16* __restrict__ B, int ldb,
    float* __restrict__ C, int ldc,
    int K, int accflag)
{
  __shared__ u16 As[128*32];
  __shared__ u16 Bs[128*32];
  const int tid = threadIdx.x;
  const int lane = tid & 63;
  const int w = tid >> 6;
  const int wr = w >> 1, wc = w & 1;
  const int m0 = blockIdx.y*128, n0 = blockIdx.x*128;

  vf4 acc[4][4];
  #pragma unroll
  for (int i=0;i<4;i++)
    #pragma unroll
    for (int j=0;j<4;j++) acc[i][j] = (vf4){0.f,0.f,0.f,0.f};

  const int c0i = w*128 + lane;
  const int c1i = c0i + 64;
  const int r0i = c0i>>2, s0i = (c0i&3) ^ ((r0i>>1)&3);
  const int r1i = c1i>>2, s1i = (c1i&3) ^ ((r1i>>1)&3);
  const u16* gA0 = A + (size_t)(m0+r0i)*lda + s0i*8;
  const u16* gA1 = A + (size_t)(m0+r1i)*lda + s1i*8;
  const u16* gB0 = B + (size_t)(n0+r0i)*ldb + s0i*8;
  const u16* gB1 = B + (size_t)(n0+r1i)*ldb + s1i*8;
  u16* lA0 = As + w*1024;
  u16* lA1 = As + w*1024 + 512;
  u16* lB0 = Bs + w*1024;
  u16* lB1 = Bs + w*1024 + 512;

  const int kg = lane>>4, lm = lane&15;

  for (int k0=0; k0<K; k0+=32){
    __syncthreads();
    gload_lds16(gA0 + k0, lA0);
    gload_lds16(gA1 + k0, lA1);
    gload_lds16(gB0 + k0, lB0);
    gload_lds16(gB1 + k0, lB1);
    __syncthreads();
    s16x8 af[4], bfr[4];
    #pragma unroll
    for (int i=0;i<4;i++){
      int ra = wr*64 + i*16 + lm;
      int sa = kg ^ ((ra>>1)&3);
      af[i] = *(const s16x8*)(As + ra*32 + sa*8);
      int rb = wc*64 + i*16 + lm;
      int sb = kg ^ ((rb>>1)&3);
      bfr[i] = *(const s16x8*)(Bs + rb*32 + sb*8);
    }
    #pragma unroll
    for (int i=0;i<4;i++)
      #pragma unroll
      for (int j=0;j<4;j++)
        acc[i][j] = __builtin_amdgcn_mfma_f32_16x16x32_bf16(af[i], bfr[j], acc[i][j], 0, 0, 0);
  }

  const int lhi = lane>>4;
  #pragma unroll
  for (int i=0;i<4;i++){
    int rbase = m0 + wr*64 + i*16 + lhi*4;
    #pragma unroll
    for (int j=0;j<4;j++){
      int cc = n0 + wc*64 + j*16 + lm;
      #pragma unroll
      for (int r=0;r<4;r++){
        float v = acc[i][j][r];
        float* pC = C + (size_t)(rbase+r)*ldc + cc;
        if (accflag) v += *pC;
        *pC = v;
      }
    }
  }
}

// ---------------- fused z projections: zx/zh/zb = h_hyper @ w0.T (+b0) ------------------
#define TK 16
#define ALD 132
__global__ __launch_bounds__(256) void zproj(
    const float* __restrict__ Ah,
    const float* __restrict__ w0x, const float* __restrict__ w0h, const float* __restrict__ w0b,
    const float* __restrict__ b0x, const float* __restrict__ b0h,
    float* __restrict__ zx, float* __restrict__ zh, float* __restrict__ zb)
{
  const float* Bm; const float* bias; float* C;
  if (blockIdx.x==0){ Bm=w0x; bias=b0x; C=zx; }
  else if (blockIdx.x==1){ Bm=w0h; bias=b0h; C=zh; }
  else { Bm=w0b; bias=nullptr; C=zb; }

  __shared__ float Asf[TK*ALD];
  __shared__ float Bsf[TK*ALD];
  const int tid = threadIdx.x;
  const int m0 = blockIdx.y*128;
  const int ar = tid>>2;
  const int ak = (tid&3)<<2;
  const int tx = tid&15, ty = tid>>4;
  float acc[8][8];
  #pragma unroll
  for (int i=0;i<8;i++)
    #pragma unroll
    for (int j=0;j<8;j++) acc[i][j]=0.f;

  const float* Ap0 = Ah + (size_t)(m0+ar)*LDT + ak;
  const float* Ap1 = Ah + (size_t)(m0+ar+64)*LDT + ak;
  const float* Bp0 = Bm + (size_t)(ar)*256 + ak;
  const float* Bp1 = Bm + (size_t)(ar+64)*256 + ak;

  for (int k0=0;k0<256;k0+=TK){
    float4 a0 = *(const float4*)(Ap0 + k0);
    float4 a1 = *(const float4*)(Ap1 + k0);
    float4 b0 = *(const float4*)(Bp0 + k0);
    float4 b1 = *(const float4*)(Bp1 + k0);
    __syncthreads();
    Asf[(ak+0)*ALD+ar]=a0.x; Asf[(ak+1)*ALD+ar]=a0.y; Asf[(ak+2)*ALD+ar]=a0.z; Asf[(ak+3)*ALD+ar]=a0.w;
    Asf[(ak+0)*ALD+ar+64]=a1.x; Asf[(ak+1)*ALD+ar+64]=a1.y; Asf[(ak+2)*ALD+ar+64]=a1.z; Asf[(ak+3)*ALD+ar+64]=a1.w;
    Bsf[(ak+0)*ALD+ar]=b0.x; Bsf[(ak+1)*ALD+ar]=b0.y; Bsf[(ak+2)*ALD+ar]=b0.z; Bsf[(ak+3)*ALD+ar]=b0.w;
    Bsf[(ak+0)*ALD+ar+64]=b1.x; Bsf[(ak+1)*ALD+ar+64]=b1.y; Bsf[(ak+2)*ALD+ar+64]=b1.z; Bsf[(ak+3)*ALD+ar+64]=b1.w;
    __syncthreads();
    #pragma unroll
    for (int kk=0;kk<TK;kk++){
      float4 av0 = *(const float4*)&Asf[kk*ALD + ty*4];
      float4 av1 = *(const float4*)&Asf[kk*ALD + ty*4 + 64];
      float4 bv0 = *(const float4*)&Bsf[kk*ALD + tx*4];
      float4 bv1 = *(const float4*)&Bsf[kk*ALD + tx*4 + 64];
      float a[8]={av0.x,av0.y,av0.z,av0.w,av1.x,av1.y,av1.z,av1.w};
      float b[8]={bv0.x,bv0.y,bv0.z,bv0.w,bv1.x,bv1.y,bv1.z,bv1.w};
      #pragma unroll
      for (int i=0;i<8;i++)
        #pragma unroll
        for (int j=0;j<8;j++) acc[i][j] += a[i]*b[j];
    }
  }
  #pragma unroll
  for (int ig=0;ig<2;ig++){
    #pragma unroll
    for (int i=0;i<4;i++){
      int row = m0 + ig*64 + ty*4 + i;
      #pragma unroll
      for (int jg=0;jg<2;jg++){
        int col = jg*64 + tx*4;
        float4 v;
        v.x=acc[ig*4+i][jg*4+0]; v.y=acc[ig*4+i][jg*4+1];
        v.z=acc[ig*4+i][jg*4+2]; v.w=acc[ig*4+i][jg*4+3];
        if (bias){ v.x+=bias[col]; v.y+=bias[col+1]; v.z+=bias[col+2]; v.w+=bias[col+3]; }
        *(float4*)(C + (size_t)row*128 + col) = v;
      }
    }
  }
}

// ---------------- hyper LSTM cell ----------------
__global__ __launch_bounds__(256) void hyper_cell(
    const float* __restrict__ lin, const float* __restrict__ c_in,
    const float* __restrict__ lnh_w, const float* __restrict__ lnh_b,
    const float* __restrict__ lnc_w, const float* __restrict__ lnc_b,
    float* __restrict__ ht_out, float* __restrict__ ct_out)
{
  int b=blockIdx.x, tid=threadIdx.x, lane=tid&63, w=tid>>6;
  __shared__ float ly[1024];
  __shared__ float red[4];
  float4 t = *(const float4*)(lin + (size_t)b*1024 + tid*4);
  float v[4]={t.x,t.y,t.z,t.w};
  float s = wave_sum(v[0]+v[1]+v[2]+v[3]);
  float mu = s*(1.f/256.f);
  float q=0.f;
  #pragma unroll
  for (int j=0;j<4;j++){ float d=v[j]-mu; q+=d*d; }
  q = wave_sum(q);
  float rs = rsqrtf(q*(1.f/256.f)+EPSV);
  int base = tid*4;
  #pragma unroll
  for (int j=0;j<4;j++) ly[base+j] = (v[j]-mu)*rs*lnh_w[base+j]+lnh_b[base+j];
  __syncthreads();
  float ig=ly[tid], fg=ly[256+tid], og=ly[512+tid], cc=ly[768+tid];
  float co = c_in[(size_t)b*LDT + 1024 + tid];
  float cn = sigf(fg+1.f)*co + sigf(ig)*tanhf(cc);
  float s2 = wave_sum(cn);
  if(lane==0) red[w]=s2;
  __syncthreads();
  float mu2=(red[0]+red[1]+red[2]+red[3])*(1.f/256.f);
  __syncthreads();
  float d = cn-mu2;
  float q2 = wave_sum(d*d);
  if(lane==0) red[w]=q2;
  __syncthreads();
  float rs2 = rsqrtf((red[0]+red[1]+red[2]+red[3])*(1.f/256.f)+EPSV);
  float hh = sigf(og)*tanhf(d*rs2*lnc_w[tid]+lnc_b[tid]);
  ht_out[(size_t)b*LDT+1024+tid]=hh;
  ct_out[(size_t)b*LDT+1024+tid]=cn;
}

// ---------------- scale apply ----------------
#define EST 68
__device__ __forceinline__ void stage_dot(
    const float* __restrict__ zp, const float* __restrict__ wp,
    int r0, int gc0, int g, int tid, int tx, int ty,
    float (&acc)[4][4], float* Zs, float* Ws)
{
  const int lr = tid>>2;
  const int le4 = (tid&3)<<2;
  float4 zv0 = *(const float4*)(zp + (size_t)(r0+lr)*128 + g*32 + le4);
  float4 zv1 = *(const float4*)(zp + (size_t)(r0+lr)*128 + g*32 + le4 + 16);
  float4 wv0 = *(const float4*)(wp + ((size_t)(g*1024 + gc0 + lr))*32 + le4);
  float4 wv1 = *(const float4*)(wp + ((size_t)(g*1024 + gc0 + lr))*32 + le4 + 16);
  __syncthreads();
  Zs[(le4+0)*EST+lr]=zv0.x; Zs[(le4+1)*EST+lr]=zv0.y; Zs[(le4+2)*EST+lr]=zv0.z; Zs[(le4+3)*EST+lr]=zv0.w;
  Zs[(le4+16)*EST+lr]=zv1.x; Zs[(le4+17)*EST+lr]=zv1.y; Zs[(le4+18)*EST+lr]=zv1.z; Zs[(le4+19)*EST+lr]=zv1.w;
  Ws[(le4+0)*EST+lr]=wv0.x; Ws[(le4+1)*EST+lr]=wv0.y; Ws[(le4+2)*EST+lr]=wv0.z; Ws[(le4+3)*EST+lr]=wv0.w;
  Ws[(le4+16)*EST+lr]=wv1.x; Ws[(le4+17)*EST+lr]=wv1.y; Ws[(le4+18)*EST+lr]=wv1.z; Ws[(le4+19)*EST+lr]=wv1.w;
  __syncthreads();
  #pragma unroll
  for (int i=0;i<4;i++)
    #pragma unroll
    for (int j=0;j<4;j++) acc[i][j]=0.f;
  #pragma unroll
  for (int e=0;e<32;e++){
    float4 av = *(const float4*)&Zs[e*EST + ty*4];
    float4 bv = *(const float4*)&Ws[e*EST + tx*4];
    float a[4]={av.x,av.y,av.z,av.w}, b[4]={bv.x,bv.y,bv.z,bv.w};
    #pragma unroll
    for (int i=0;i<4;i++)
      #pragma unroll
      for (int j=0;j<4;j++) acc[i][j]+=a[i]*b[j];
  }
}

__global__ __launch_bounds__(256) void scale_apply(
  const float* __restrict__ Wx, const float* __restrict__ Wh,
  const float* __restrict__ zx, const float* __restrict__ zh, const float* __restrict__ zb,
  const float* __restrict__ w1x, const float* __restrict__ w1h, const float* __restrict__ w1b,
  float* __restrict__ glin)
{
  __shared__ float Zs[32*EST], Ws[32*EST];
  int tid=threadIdx.x;
  int c0=blockIdx.x*64, r0=blockIdx.y*64;
  int g=c0>>10, gc0=c0&1023;
  int tx=tid&15, ty=tid>>4;
  float acc[4][4], gval[4][4];

  stage_dot(zx,w1x,r0,gc0,g,tid,tx,ty,acc,Zs,Ws);
  #pragma unroll
  for (int i=0;i<4;i++){
    float4 wv = *(const float4*)(Wx + (size_t)(r0+ty*4+i)*4096 + c0 + tx*4);
    gval[i][0]=acc[i][0]*wv.x; gval[i][1]=acc[i][1]*wv.y;
    gval[i][2]=acc[i][2]*wv.z; gval[i][3]=acc[i][3]*wv.w;
  }
  stage_dot(zh,w1h,r0,gc0,g,tid,tx,ty,acc,Zs,Ws);
  #pragma unroll
  for (int i=0;i<4;i++){
    float4 wv = *(const float4*)(Wh + (size_t)(r0+ty*4+i)*4096 + c0 + tx*4);
    gval[i][0]+=acc[i][0]*wv.x; gval[i][1]+=acc[i][1]*wv.y;
    gval[i][2]+=acc[i][2]*wv.z; gval[i][3]+=acc[i][3]*wv.w;
  }
  stage_dot(zb,w1b,r0,gc0,g,tid,tx,ty,acc,Zs,Ws);
  #pragma unroll
  for (int i=0;i<4;i++){
    float4 v;
    v.x=gval[i][0]+acc[i][0]; v.y=gval[i][1]+acc[i][1];
    v.z=gval[i][2]+acc[i][2]; v.w=gval[i][3]+acc[i][3];
    *(float4*)(glin + (size_t)(r0+ty*4+i)*4096 + c0 + tx*4) = v;
  }
}

// ---------------- main LSTM cell ----------------
__global__ __launch_bounds__(256) void main_cell(
    const float* __restrict__ glin, const float* __restrict__ c_in,
    const float* __restrict__ lnh_w, const float* __restrict__ lnh_b,
    const float* __restrict__ lnc_w, const float* __restrict__ lnc_b,
    float* __restrict__ h_out, float* __restrict__ ht_out, float* __restrict__ ct_out)
{
  int b=blockIdx.x, tid=threadIdx.x, lane=tid&63, w=tid>>6;
  __shared__ float red[16];
  float v[4][4];
  #pragma unroll
  for (int g=0;g<4;g++){
    float4 t = *(const float4*)(glin + (size_t)b*4096 + g*1024 + tid*4);
    v[g][0]=t.x; v[g][1]=t.y; v[g][2]=t.z; v[g][3]=t.w;
  }
  float mu[4], rs[4];
  #pragma unroll
  for (int g=0;g<4;g++){
    float s = wave_sum(v[g][0]+v[g][1]+v[g][2]+v[g][3]);
    if(lane==0) red[g*4+w]=s;
  }
  __syncthreads();
  #pragma unroll
  for (int g=0;g<4;g++) mu[g]=(red[g*4]+red[g*4+1]+red[g*4+2]+red[g*4+3])*(1.f/1024.f);
  __syncthreads();
  #pragma unroll
  for (int g=0;g<4;g++){
    float q=0.f;
    #pragma unroll
    for (int j=0;j<4;j++){ float d=v[g][j]-mu[g]; q+=d*d; }
    q = wave_sum(q);
    if(lane==0) red[g*4+w]=q;
  }
  __syncthreads();
  #pragma unroll
  for (int g=0;g<4;g++) rs[g]=rsqrtf((red[g*4]+red[g*4+1]+red[g*4+2]+red[g*4+3])*(1.f/1024.f)+EPSV);
  int o0=tid*4;
  float y[4][4];
  #pragma unroll
  for (int g=0;g<4;g++)
    #pragma unroll
    for (int j=0;j<4;j++){
      int idx=g*1024+o0+j;
      y[g][j]=(v[g][j]-mu[g])*rs[g]*lnh_w[idx]+lnh_b[idx];
    }
  float4 ct = *(const float4*)(c_in + (size_t)b*LDT + o0);
  float co[4]={ct.x,ct.y,ct.z,ct.w};
  float cn[4];
  #pragma unroll
  for (int j=0;j<4;j++) cn[j]=sigf(y[1][j]+1.f)*co[j] + sigf(y[0][j])*tanhf(y[3][j]);
  float s = wave_sum(cn[0]+cn[1]+cn[2]+cn[3]);
  __syncthreads();
  if(lane==0) red[w]=s;
  __syncthreads();
  float muc=(red[0]+red[1]+red[2]+red[3])*(1.f/1024.f);
  __syncthreads();
  float q=0.f;
  #pragma unroll
  for (int j=0;j<4;j++){ float d=cn[j]-muc; q+=d*d; }
  q=wave_sum(q);
  if(lane==0) red[w]=q;
  __syncthreads();
  float rsc=rsqrtf((red[0]+red[1]+red[2]+red[3])*(1.f/1024.f)+EPSV);
  float h[4];
  #pragma unroll
  for (int j=0;j<4;j++) h[j]=sigf(y[2][j])*tanhf((cn[j]-muc)*rsc*lnc_w[o0+j]+lnc_b[o0+j]);
  float4 hv; hv.x=h[0]; hv.y=h[1]; hv.z=h[2]; hv.w=h[3];
  float4 cv; cv.x=cn[0]; cv.y=cn[1]; cv.z=cn[2]; cv.w=cn[3];
  *(float4*)(h_out +(size_t)b*1024+o0) = hv;
  *(float4*)(ht_out+(size_t)b*LDT +o0) = hv;
  *(float4*)(ct_out+(size_t)b*LDT +o0) = cv;
}

extern "C" void kernel_launch(void* const* d_in, const int* in_sizes, int n_in,
                              void* d_out, int out_size, void* d_ws, size_t ws_size,
                              hipStream_t stream) {
  (void)in_sizes; (void)n_in; (void)out_size; (void)ws_size;
  const float* x         = (const float*)d_in[0];
  const float* h_total   = (const float*)d_in[1];
  const float* c_total   = (const float*)d_in[2];
  const float* hyp_w_ih  = (const float*)d_in[3];
  const float* hyp_w_hh  = (const float*)d_in[4];
  const float* hyp_lnh_w = (const float*)d_in[5];
  const float* hyp_lnh_b = (const float*)d_in[6];
  const float* hyp_lnc_w = (const float*)d_in[7];
  const float* hyp_lnc_b = (const float*)d_in[8];
  const float* w_ih      = (const float*)d_in[9];
  const float* w_hh      = (const float*)d_in[10];
  const float* lnh_w     = (const float*)d_in[11];
  const float* lnh_b     = (const float*)d_in[12];
  const float* lnc_w     = (const float*)d_in[13];
  const float* lnc_b     = (const float*)d_in[14];
  const float* sx_w0     = (const float*)d_in[15];
  const float* sx_b0     = (const float*)d_in[16];
  const float* sx_w1     = (const float*)d_in[17];
  const float* sh_w0     = (const float*)d_in[18];
  const float* sh_b0     = (const float*)d_in[19];
  const float* sh_w1     = (const float*)d_in[20];
  const float* bh_w0     = (const float*)d_in[21];
  const float* bh_w1     = (const float*)d_in[22];

  float* out    = (float*)d_out;
  float* h_out  = out;
  float* ht_out = out + (size_t)BB*1024;
  float* ct_out = ht_out + (size_t)BB*LDT;

  char* p = (char*)d_ws;
  float* lin = (float*)p;  p += (size_t)4096*1024*4;
  float* Wx  = (float*)p;  p += (size_t)4096*4096*4;
  float* Wh  = (float*)p;  p += (size_t)4096*4096*4;
  float* zx  = (float*)p;  p += (size_t)4096*128*4;
  float* zh  = (float*)p;  p += (size_t)4096*128*4;
  float* zb  = (float*)p;  p += (size_t)4096*128*4;
  u16* Hbig  = (u16*)p;    p += (size_t)4096*3072*2;
  u16* Wihb  = (u16*)p;    p += (size_t)4096*1536*2;
  u16* Whhb  = (u16*)p;    p += (size_t)4096*3072*2;
  u16* XHhyp = (u16*)p;    p += (size_t)4096*2304*2;   // [x split 1536 | h_hyper split 768]
  u16* Whyp  = (u16*)p;    p += (size_t)1024*2304*2;   // [w_ih split 1536 | w_hh split 768]

  // split-bf16 conversions (mode 0 = A side [hi|lo|hi], mode 1 = B side [hi|hi|lo])
  cvt_split<<<dim3(2,4096),64,0,stream>>>(x, 512, 512, XHhyp, 2304, 0);
  cvt_split<<<dim3(1,4096),64,0,stream>>>(h_total+1024, LDT, 256, XHhyp+1536, 2304, 0);
  cvt_split<<<dim3(4,4096),64,0,stream>>>(h_total, LDT, 1024, Hbig, 3072, 0);
  cvt_split<<<dim3(2,4096),64,0,stream>>>(w_ih, 512, 512, Wihb, 1536, 1);
  cvt_split<<<dim3(4,4096),64,0,stream>>>(w_hh, 1024, 1024, Whhb, 3072, 1);
  cvt_split<<<dim3(2,1024),64,0,stream>>>(hyp_w_ih, 512, 512, Whyp, 2304, 1);
  cvt_split<<<dim3(1,1024),64,0,stream>>>(hyp_w_hh, 256, 256, Whyp+1536, 2304, 1);

  // hyper linear (combined K'=2304): lin = x@hyp_w_ih.T + h_hyper@hyp_w_hh.T
  gemm_bf16nt<<<dim3(8,32),256,0,stream>>>(XHhyp,2304, Whyp,2304, lin,1024, 2304, 0);
  // main big GEMMs on the 256x256 8-phase kernel
  gemm256<<<dim3(16,16),512,0,stream>>>(XHhyp,2304, Wihb,1536, Wx,4096, 1536);
  gemm256<<<dim3(16,16),512,0,stream>>>(Hbig,3072, Whhb,3072, Wh,4096, 3072);

  hyper_cell<<<4096,256,0,stream>>>(lin, c_total, hyp_lnh_w, hyp_lnh_b, hyp_lnc_w, hyp_lnc_b, ht_out, ct_out);

  zproj<<<dim3(3,32),256,0,stream>>>(ht_out+1024, sx_w0, sh_w0, bh_w0, sx_b0, sh_b0, zx, zh, zb);

  scale_apply<<<dim3(64,64),256,0,stream>>>(Wx, Wh, zx, zh, zb, sx_w1, sh_w1, bh_w1, Wx);
  main_cell<<<4096,256,0,stream>>>(Wx, c_total, lnh_w, lnh_b, lnc_w, lnc_b, h_out, ht_out, ct_out);
}

// Round 6
// 517.950 us; speedup vs baseline: 2.0412x; 1.0850x over previous
//
#include <hip/hip_runtime.h>
#include <math.h>

typedef unsigned short u16;
typedef unsigned int u32;
typedef unsigned long long u64;
typedef __attribute__((ext_vector_type(4))) float vf4;
typedef __attribute__((ext_vector_type(8))) short s16x8;

#define EPSV 1e-5f
#define BB 4096
#define LDT 1280   // H + HH

__device__ __forceinline__ float sigf(float x){
  float e = expf(-fabsf(x));
  float r = 1.f/(1.f+e);
  return x>=0.f ? r : 1.f-r;
}

__device__ __forceinline__ float wave_sum(float v){
  #pragma unroll
  for (int m=32;m>0;m>>=1) v += __shfl_xor(v, m);
  return v;
}

__device__ __forceinline__ u16 f2bf(float f){
  u32 u = __builtin_bit_cast(u32, f);
  u32 r = u + 0x7FFFu + ((u>>16)&1u);
  return (u16)(r>>16);
}
__device__ __forceinline__ float bf2f(u16 h){
  u32 u = ((u32)h)<<16;
  return __builtin_bit_cast(float, u);
}

#define AS1 __attribute__((address_space(1)))
#define AS3 __attribute__((address_space(3)))
__device__ __forceinline__ void gload_lds16(const u16* g, u16* l){
  __builtin_amdgcn_global_load_lds((const AS1 void*)g, (AS3 void*)l, 16, 0, 0);
}

// ---------------- split conversion (Markidis 3-term, ASYMMETRIC layouts) ----------------
// mode 0 (A side / activations): out row = [ hi | lo | hi ]
// mode 1 (B side / weights):     out row = [ hi | hi | lo ]
__global__ __launch_bounds__(64) void cvt_split(const float* __restrict__ in, int ld_in, int K,
                                                u16* __restrict__ out, int ld_out, int mode)
{
  int row = blockIdx.y;
  int c4 = (blockIdx.x*64 + threadIdx.x)*4;
  if (c4 >= K) return;
  float4 v = *(const float4*)(in + (size_t)row*ld_in + c4);
  float vv[4] = {v.x, v.y, v.z, v.w};
  u64 hi=0, lo=0;
  #pragma unroll
  for (int j=0;j<4;j++){
    u16 h = f2bf(vv[j]);
    u16 l = f2bf(vv[j] - bf2f(h));
    hi |= (u64)h << (16*j);
    lo |= (u64)l << (16*j);
  }
  u16* o = out + (size_t)row*ld_out + c4;
  *(u64*)(o) = hi;
  if (mode == 0){
    *(u64*)(o + K)   = lo;
    *(u64*)(o + 2*K) = hi;
  } else {
    *(u64*)(o + K)   = hi;
    *(u64*)(o + 2*K) = lo;
  }
}

// ================= 256x256 8-phase bf16 MFMA NT GEMM (T2+T3+T4+T5) =================
// 512 threads = 8 waves (2M x 4N), BK=64, double-buffered 128KiB LDS.
// m201 rhythm: ds_reads issued BEFORE the leading barrier (latency hides under
// barrier wait / other waves' MFMA); A-frags register-pipelined one phase ahead;
// all 8 staging loads at phase 0 (4-phase prefetch distance); per-wave vmcnt
// drain at end of phase 3 (own loads ~3.5 phases old) + barrier.
template<int P>
__device__ __forceinline__ void load_afrag(const u16* Ab, int wm, int lm, int kg, s16x8 af[2][2]){
  #pragma unroll
  for (int fl=0; fl<2; fl++)
    #pragma unroll
    for (int kk=0; kk<2; kk++){
      int row = wm*128 + (P*2+fl)*16 + lm;
      int sl = (kk*4+kg) ^ (row&7);
      af[fl][kk] = *(const s16x8*)(Ab + row*64 + sl*8);
    }
}

template<int P>
__device__ __forceinline__ void mfma_phase(vf4 acc[8][4], const s16x8 af[2][2], const s16x8 bf[4][2]){
  __builtin_amdgcn_s_setprio(1);
  #pragma unroll
  for (int fl=0; fl<2; fl++)
    #pragma unroll
    for (int j=0; j<4; j++)
      #pragma unroll
      for (int kk=0; kk<2; kk++)
        acc[P*2+fl][j] = __builtin_amdgcn_mfma_f32_16x16x32_bf16(af[fl][kk], bf[j][kk], acc[P*2+fl][j], 0, 0, 0);
  __builtin_amdgcn_s_setprio(0);
}

__global__ __launch_bounds__(512, 2) void gemm256(
    const u16* __restrict__ A, int lda,
    const u16* __restrict__ B, int ldb,
    float* __restrict__ C, int ldc, int K)
{
  __shared__ u16 As[2][256*64];
  __shared__ u16 Bs[2][256*64];
  const int tid = threadIdx.x;
  const int lane = tid & 63;
  const int wid = tid >> 6;
  const int wm = wid >> 2, wn = wid & 3;
  const int m0 = blockIdx.y*256, n0 = blockIdx.x*256;
  const int kg = lane>>4, lm = lane&15;

  vf4 acc[8][4];
  #pragma unroll
  for (int i=0;i<8;i++)
    #pragma unroll
    for (int j=0;j<4;j++) acc[i][j] = (vf4){0.f,0.f,0.f,0.f};

  // staging map: 2048 16B-chunks per matrix per K-tile; thread covers chunk q*512+tid.
  // chunk c: row=c>>3, phys slot=c&7; source col16 = slot ^ (row&7) (inverse swizzle).
  const u16* gA[4]; const u16* gB[4]; int ldsOff[4];
  #pragma unroll
  for (int q=0;q<4;q++){
    int c = q*512 + tid;
    int row = c>>3, slot = c&7;
    int scol = slot ^ (row&7);
    gA[q] = A + (size_t)(m0+row)*lda + scol*8;
    gB[q] = B + (size_t)(n0+row)*ldb + scol*8;
    ldsOff[q] = (q*512 + wid*64)*8;   // wave-uniform dest base (lane*16B appended by HW)
  }

  const int NT = K>>6;
  // prologue: stage tile 0 into buf 0
  #pragma unroll
  for (int q=0;q<4;q++) gload_lds16(gA[q], &As[0][ldsOff[q]]);
  #pragma unroll
  for (int q=0;q<4;q++) gload_lds16(gB[q], &Bs[0][ldsOff[q]]);
  asm volatile("s_waitcnt vmcnt(0)" ::: "memory");
  __builtin_amdgcn_s_barrier();

  s16x8 afA[2][2], afB[2][2], bfrag[4][2];

  for (int t=0; t<NT; ++t){
    const int cur = t&1, nxt = cur^1;
    const u16* Ab = As[cur];
    const u16* Bb = Bs[cur];

    // ---- phase 0: pre-barrier reads (af0, af1, all bfrag) + stage tile t+1 ----
    load_afrag<0>(Ab, wm, lm, kg, afA);
    #pragma unroll
    for (int j=0;j<4;j++)
      #pragma unroll
      for (int kk=0;kk<2;kk++){
        int row = wn*64 + j*16 + lm;
        int sl = (kk*4+kg) ^ (row&7);
        bfrag[j][kk] = *(const s16x8*)(Bb + row*64 + sl*8);
      }
    load_afrag<1>(Ab, wm, lm, kg, afB);
    if (t+1 < NT){
      const int kb = (t+1)<<6;
      #pragma unroll
      for (int q=0;q<4;q++) gload_lds16(gA[q]+kb, &As[nxt][ldsOff[q]]);
      #pragma unroll
      for (int q=0;q<4;q++) gload_lds16(gB[q]+kb, &Bs[nxt][ldsOff[q]]);
    }
    __builtin_amdgcn_sched_barrier(0);
    __builtin_amdgcn_s_barrier();
    mfma_phase<0>(acc, afA, bfrag);
    __builtin_amdgcn_s_barrier();

    // ---- phase 1: read af2 (for phase 2), compute af1 ----
    load_afrag<2>(Ab, wm, lm, kg, afA);
    __builtin_amdgcn_sched_barrier(0);
    __builtin_amdgcn_s_barrier();
    mfma_phase<1>(acc, afB, bfrag);
    __builtin_amdgcn_s_barrier();

    // ---- phase 2: read af3, compute af2 ----
    load_afrag<3>(Ab, wm, lm, kg, afB);
    __builtin_amdgcn_sched_barrier(0);
    __builtin_amdgcn_s_barrier();
    mfma_phase<2>(acc, afA, bfrag);
    __builtin_amdgcn_s_barrier();

    // ---- phase 3: compute af3, then drain own staged loads + barrier ----
    __builtin_amdgcn_sched_barrier(0);
    __builtin_amdgcn_s_barrier();
    mfma_phase<3>(acc, afB, bfrag);
    asm volatile("s_waitcnt vmcnt(0)" ::: "memory");   // own 8 loads, issued ~3.5 phases ago
    __builtin_amdgcn_s_barrier();                       // => all waves' tile t+1 landed
  }

  // C/D layout (m89-verified): col = lane&15, row = (lane>>4)*4 + reg
  #pragma unroll
  for (int f=0; f<8; f++){
    int rb = m0 + wm*128 + f*16 + kg*4;
    #pragma unroll
    for (int j=0; j<4; j++){
      int cc = n0 + wn*64 + j*16 + lm;
      #pragma unroll
      for (int r=0; r<4; r++)
        C[(size_t)(rb+r)*ldc + cc] = acc[f][j][r];
    }
  }
}

// ---------------- 128x128 bf16 MFMA NT GEMM (m97 structure) — hyper path ----------------
__global__ __launch_bounds__(256) void gemm_bf16nt(
    const u16* __restrict__ A, int lda,
    const u16* __restrict__ B, int ldb,
    float* __restrict__ C, int ldc,
    int K, int accflag)
{
  __shared__ u16 As[128*32];
  __shared__ u16 Bs[128*32];
  const int tid = threadIdx.x;
  const int lane = tid & 63;
  const int w = tid >> 6;
  const int wr = w >> 1, wc = w & 1;
  const int m0 = blockIdx.y*128, n0 = blockIdx.x*128;

  vf4 acc[4][4];
  #pragma unroll
  for (int i=0;i<4;i++)
    #pragma unroll
    for (int j=0;j<4;j++) acc[i][j] = (vf4){0.f,0.f,0.f,0.f};

  const int c0i = w*128 + lane;
  const int c1i = c0i + 64;
  const int r0i = c0i>>2, s0i = (c0i&3) ^ ((r0i>>1)&3);
  const int r1i = c1i>>2, s1i = (c1i&3) ^ ((r1i>>1)&3);
  const u16* gA0 = A + (size_t)(m0+r0i)*lda + s0i*8;
  const u16* gA1 = A + (size_t)(m0+r1i)*lda + s1i*8;
  const u16* gB0 = B + (size_t)(n0+r0i)*ldb + s0i*8;
  const u16* gB1 = B + (size_t)(n0+r1i)*ldb + s1i*8;
  u16* lA0 = As + w*1024;
  u16* lA1 = As + w*1024 + 512;
  u16* lB0 = Bs + w*1024;
  u16* lB1 = Bs + w*1024 + 512;

  const int kg = lane>>4, lm = lane&15;

  for (int k0=0; k0<K; k0+=32){
    __syncthreads();
    gload_lds16(gA0 + k0, lA0);
    gload_lds16(gA1 + k0, lA1);
    gload_lds16(gB0 + k0, lB0);
    gload_lds16(gB1 + k0, lB1);
    __syncthreads();
    s16x8 af[4], bfr[4];
    #pragma unroll
    for (int i=0;i<4;i++){
      int ra = wr*64 + i*16 + lm;
      int sa = kg ^ ((ra>>1)&3);
      af[i] = *(const s16x8*)(As + ra*32 + sa*8);
      int rb = wc*64 + i*16 + lm;
      int sb = kg ^ ((rb>>1)&3);
      bfr[i] = *(const s16x8*)(Bs + rb*32 + sb*8);
    }
    #pragma unroll
    for (int i=0;i<4;i++)
      #pragma unroll
      for (int j=0;j<4;j++)
        acc[i][j] = __builtin_amdgcn_mfma_f32_16x16x32_bf16(af[i], bfr[j], acc[i][j], 0, 0, 0);
  }

  const int lhi = lane>>4;
  #pragma unroll
  for (int i=0;i<4;i++){
    int rbase = m0 + wr*64 + i*16 + lhi*4;
    #pragma unroll
    for (int j=0;j<4;j++){
      int cc = n0 + wc*64 + j*16 + lm;
      #pragma unroll
      for (int r=0;r<4;r++){
        float v = acc[i][j][r];
        float* pC = C + (size_t)(rbase+r)*ldc + cc;
        if (accflag) v += *pC;
        *pC = v;
      }
    }
  }
}

// ---------------- fused z projections: zx/zh/zb = h_hyper @ w0.T (+b0) ------------------
#define TK 16
#define ALD 132
__global__ __launch_bounds__(256) void zproj(
    const float* __restrict__ Ah,
    const float* __restrict__ w0x, const float* __restrict__ w0h, const float* __restrict__ w0b,
    const float* __restrict__ b0x, const float* __restrict__ b0h,
    float* __restrict__ zx, float* __restrict__ zh, float* __restrict__ zb)
{
  const float* Bm; const float* bias; float* C;
  if (blockIdx.x==0){ Bm=w0x; bias=b0x; C=zx; }
  else if (blockIdx.x==1){ Bm=w0h; bias=b0h; C=zh; }
  else { Bm=w0b; bias=nullptr; C=zb; }

  __shared__ float Asf[TK*ALD];
  __shared__ float Bsf[TK*ALD];
  const int tid = threadIdx.x;
  const int m0 = blockIdx.y*128;
  const int ar = tid>>2;
  const int ak = (tid&3)<<2;
  const int tx = tid&15, ty = tid>>4;
  float acc[8][8];
  #pragma unroll
  for (int i=0;i<8;i++)
    #pragma unroll
    for (int j=0;j<8;j++) acc[i][j]=0.f;

  const float* Ap0 = Ah + (size_t)(m0+ar)*LDT + ak;
  const float* Ap1 = Ah + (size_t)(m0+ar+64)*LDT + ak;
  const float* Bp0 = Bm + (size_t)(ar)*256 + ak;
  const float* Bp1 = Bm + (size_t)(ar+64)*256 + ak;

  for (int k0=0;k0<256;k0+=TK){
    float4 a0 = *(const float4*)(Ap0 + k0);
    float4 a1 = *(const float4*)(Ap1 + k0);
    float4 b0 = *(const float4*)(Bp0 + k0);
    float4 b1 = *(const float4*)(Bp1 + k0);
    __syncthreads();
    Asf[(ak+0)*ALD+ar]=a0.x; Asf[(ak+1)*ALD+ar]=a0.y; Asf[(ak+2)*ALD+ar]=a0.z; Asf[(ak+3)*ALD+ar]=a0.w;
    Asf[(ak+0)*ALD+ar+64]=a1.x; Asf[(ak+1)*ALD+ar+64]=a1.y; Asf[(ak+2)*ALD+ar+64]=a1.z; Asf[(ak+3)*ALD+ar+64]=a1.w;
    Bsf[(ak+0)*ALD+ar]=b0.x; Bsf[(ak+1)*ALD+ar]=b0.y; Bsf[(ak+2)*ALD+ar]=b0.z; Bsf[(ak+3)*ALD+ar]=b0.w;
    Bsf[(ak+0)*ALD+ar+64]=b1.x; Bsf[(ak+1)*ALD+ar+64]=b1.y; Bsf[(ak+2)*ALD+ar+64]=b1.z; Bsf[(ak+3)*ALD+ar+64]=b1.w;
    __syncthreads();
    #pragma unroll
    for (int kk=0;kk<TK;kk++){
      float4 av0 = *(const float4*)&Asf[kk*ALD + ty*4];
      float4 av1 = *(const float4*)&Asf[kk*ALD + ty*4 + 64];
      float4 bv0 = *(const float4*)&Bsf[kk*ALD + tx*4];
      float4 bv1 = *(const float4*)&Bsf[kk*ALD + tx*4 + 64];
      float a[8]={av0.x,av0.y,av0.z,av0.w,av1.x,av1.y,av1.z,av1.w};
      float b[8]={bv0.x,bv0.y,bv0.z,bv0.w,bv1.x,bv1.y,bv1.z,bv1.w};
      #pragma unroll
      for (int i=0;i<8;i++)
        #pragma unroll
        for (int j=0;j<8;j++) acc[i][j] += a[i]*b[j];
    }
  }
  #pragma unroll
  for (int ig=0;ig<2;ig++){
    #pragma unroll
    for (int i=0;i<4;i++){
      int row = m0 + ig*64 + ty*4 + i;
      #pragma unroll
      for (int jg=0;jg<2;jg++){
        int col = jg*64 + tx*4;
        float4 v;
        v.x=acc[ig*4+i][jg*4+0]; v.y=acc[ig*4+i][jg*4+1];
        v.z=acc[ig*4+i][jg*4+2]; v.w=acc[ig*4+i][jg*4+3];
        if (bias){ v.x+=bias[col]; v.y+=bias[col+1]; v.z+=bias[col+2]; v.w+=bias[col+3]; }
        *(float4*)(C + (size_t)row*128 + col) = v;
      }
    }
  }
}

// ---------------- hyper LSTM cell ----------------
__global__ __launch_bounds__(256) void hyper_cell(
    const float* __restrict__ lin, const float* __restrict__ c_in,
    const float* __restrict__ lnh_w, const float* __restrict__ lnh_b,
    const float* __restrict__ lnc_w, const float* __restrict__ lnc_b,
    float* __restrict__ ht_out, float* __restrict__ ct_out)
{
  int b=blockIdx.x, tid=threadIdx.x, lane=tid&63, w=tid>>6;
  __shared__ float ly[1024];
  __shared__ float red[4];
  float4 t = *(const float4*)(lin + (size_t)b*1024 + tid*4);
  float v[4]={t.x,t.y,t.z,t.w};
  float s = wave_sum(v[0]+v[1]+v[2]+v[3]);
  float mu = s*(1.f/256.f);
  float q=0.f;
  #pragma unroll
  for (int j=0;j<4;j++){ float d=v[j]-mu; q+=d*d; }
  q = wave_sum(q);
  float rs = rsqrtf(q*(1.f/256.f)+EPSV);
  int base = tid*4;
  #pragma unroll
  for (int j=0;j<4;j++) ly[base+j] = (v[j]-mu)*rs*lnh_w[base+j]+lnh_b[base+j];
  __syncthreads();
  float ig=ly[tid], fg=ly[256+tid], og=ly[512+tid], cc=ly[768+tid];
  float co = c_in[(size_t)b*LDT + 1024 + tid];
  float cn = sigf(fg+1.f)*co + sigf(ig)*tanhf(cc);
  float s2 = wave_sum(cn);
  if(lane==0) red[w]=s2;
  __syncthreads();
  float mu2=(red[0]+red[1]+red[2]+red[3])*(1.f/256.f);
  __syncthreads();
  float d = cn-mu2;
  float q2 = wave_sum(d*d);
  if(lane==0) red[w]=q2;
  __syncthreads();
  float rs2 = rsqrtf((red[0]+red[1]+red[2]+red[3])*(1.f/256.f)+EPSV);
  float hh = sigf(og)*tanhf(d*rs2*lnc_w[tid]+lnc_b[tid]);
  ht_out[(size_t)b*LDT+1024+tid]=hh;
  ct_out[(size_t)b*LDT+1024+tid]=cn;
}

// ---------------- scale apply ----------------
#define EST 68
__device__ __forceinline__ void stage_dot(
    const float* __restrict__ zp, const float* __restrict__ wp,
    int r0, int gc0, int g, int tid, int tx, int ty,
    float (&acc)[4][4], float* Zs, float* Ws)
{
  const int lr = tid>>2;
  const int le4 = (tid&3)<<2;
  float4 zv0 = *(const float4*)(zp + (size_t)(r0+lr)*128 + g*32 + le4);
  float4 zv1 = *(const float4*)(zp + (size_t)(r0+lr)*128 + g*32 + le4 + 16);
  float4 wv0 = *(const float4*)(wp + ((size_t)(g*1024 + gc0 + lr))*32 + le4);
  float4 wv1 = *(const float4*)(wp + ((size_t)(g*1024 + gc0 + lr))*32 + le4 + 16);
  __syncthreads();
  Zs[(le4+0)*EST+lr]=zv0.x; Zs[(le4+1)*EST+lr]=zv0.y; Zs[(le4+2)*EST+lr]=zv0.z; Zs[(le4+3)*EST+lr]=zv0.w;
  Zs[(le4+16)*EST+lr]=zv1.x; Zs[(le4+17)*EST+lr]=zv1.y; Zs[(le4+18)*EST+lr]=zv1.z; Zs[(le4+19)*EST+lr]=zv1.w;
  Ws[(le4+0)*EST+lr]=wv0.x; Ws[(le4+1)*EST+lr]=wv0.y; Ws[(le4+2)*EST+lr]=wv0.z; Ws[(le4+3)*EST+lr]=wv0.w;
  Ws[(le4+16)*EST+lr]=wv1.x; Ws[(le4+17)*EST+lr]=wv1.y; Ws[(le4+18)*EST+lr]=wv1.z; Ws[(le4+19)*EST+lr]=wv1.w;
  __syncthreads();
  #pragma unroll
  for (int i=0;i<4;i++)
    #pragma unroll
    for (int j=0;j<4;j++) acc[i][j]=0.f;
  #pragma unroll
  for (int e=0;e<32;e++){
    float4 av = *(const float4*)&Zs[e*EST + ty*4];
    float4 bv = *(const float4*)&Ws[e*EST + tx*4];
    float a[4]={av.x,av.y,av.z,av.w}, b[4]={bv.x,bv.y,bv.z,bv.w};
    #pragma unroll
    for (int i=0;i<4;i++)
      #pragma unroll
      for (int j=0;j<4;j++) acc[i][j]+=a[i]*b[j];
  }
}

__global__ __launch_bounds__(256) void scale_apply(
  const float* __restrict__ Wx, const float* __restrict__ Wh,
  const float* __restrict__ zx, const float* __restrict__ zh, const float* __restrict__ zb,
  const float* __restrict__ w1x, const float* __restrict__ w1h, const float* __restrict__ w1b,
  float* __restrict__ glin)
{
  __shared__ float Zs[32*EST], Ws[32*EST];
  int tid=threadIdx.x;
  int c0=blockIdx.x*64, r0=blockIdx.y*64;
  int g=c0>>10, gc0=c0&1023;
  int tx=tid&15, ty=tid>>4;
  float acc[4][4], gval[4][4];

  stage_dot(zx,w1x,r0,gc0,g,tid,tx,ty,acc,Zs,Ws);
  #pragma unroll
  for (int i=0;i<4;i++){
    float4 wv = *(const float4*)(Wx + (size_t)(r0+ty*4+i)*4096 + c0 + tx*4);
    gval[i][0]=acc[i][0]*wv.x; gval[i][1]=acc[i][1]*wv.y;
    gval[i][2]=acc[i][2]*wv.z; gval[i][3]=acc[i][3]*wv.w;
  }
  stage_dot(zh,w1h,r0,gc0,g,tid,tx,ty,acc,Zs,Ws);
  #pragma unroll
  for (int i=0;i<4;i++){
    float4 wv = *(const float4*)(Wh + (size_t)(r0+ty*4+i)*4096 + c0 + tx*4);
    gval[i][0]+=acc[i][0]*wv.x; gval[i][1]+=acc[i][1]*wv.y;
    gval[i][2]+=acc[i][2]*wv.z; gval[i][3]+=acc[i][3]*wv.w;
  }
  stage_dot(zb,w1b,r0,gc0,g,tid,tx,ty,acc,Zs,Ws);
  #pragma unroll
  for (int i=0;i<4;i++){
    float4 v;
    v.x=gval[i][0]+acc[i][0]; v.y=gval[i][1]+acc[i][1];
    v.z=gval[i][2]+acc[i][2]; v.w=gval[i][3]+acc[i][3];
    *(float4*)(glin + (size_t)(r0+ty*4+i)*4096 + c0 + tx*4) = v;
  }
}

// ---------------- main LSTM cell ----------------
__global__ __launch_bounds__(256) void main_cell(
    const float* __restrict__ glin, const float* __restrict__ c_in,
    const float* __restrict__ lnh_w, const float* __restrict__ lnh_b,
    const float* __restrict__ lnc_w, const float* __restrict__ lnc_b,
    float* __restrict__ h_out, float* __restrict__ ht_out, float* __restrict__ ct_out)
{
  int b=blockIdx.x, tid=threadIdx.x, lane=tid&63, w=tid>>6;
  __shared__ float red[16];
  float v[4][4];
  #pragma unroll
  for (int g=0;g<4;g++){
    float4 t = *(const float4*)(glin + (size_t)b*4096 + g*1024 + tid*4);
    v[g][0]=t.x; v[g][1]=t.y; v[g][2]=t.z; v[g][3]=t.w;
  }
  float mu[4], rs[4];
  #pragma unroll
  for (int g=0;g<4;g++){
    float s = wave_sum(v[g][0]+v[g][1]+v[g][2]+v[g][3]);
    if(lane==0) red[g*4+w]=s;
  }
  __syncthreads();
  #pragma unroll
  for (int g=0;g<4;g++) mu[g]=(red[g*4]+red[g*4+1]+red[g*4+2]+red[g*4+3])*(1.f/1024.f);
  __syncthreads();
  #pragma unroll
  for (int g=0;g<4;g++){
    float q=0.f;
    #pragma unroll
    for (int j=0;j<4;j++){ float d=v[g][j]-mu[g]; q+=d*d; }
    q = wave_sum(q);
    if(lane==0) red[g*4+w]=q;
  }
  __syncthreads();
  #pragma unroll
  for (int g=0;g<4;g++) rs[g]=rsqrtf((red[g*4]+red[g*4+1]+red[g*4+2]+red[g*4+3])*(1.f/1024.f)+EPSV);
  int o0=tid*4;
  float y[4][4];
  #pragma unroll
  for (int g=0;g<4;g++)
    #pragma unroll
    for (int j=0;j<4;j++){
      int idx=g*1024+o0+j;
      y[g][j]=(v[g][j]-mu[g])*rs[g]*lnh_w[idx]+lnh_b[idx];
    }
  float4 ct = *(const float4*)(c_in + (size_t)b*LDT + o0);
  float co[4]={ct.x,ct.y,ct.z,ct.w};
  float cn[4];
  #pragma unroll
  for (int j=0;j<4;j++) cn[j]=sigf(y[1][j]+1.f)*co[j] + sigf(y[0][j])*tanhf(y[3][j]);
  float s = wave_sum(cn[0]+cn[1]+cn[2]+cn[3]);
  __syncthreads();
  if(lane==0) red[w]=s;
  __syncthreads();
  float muc=(red[0]+red[1]+red[2]+red[3])*(1.f/1024.f);
  __syncthreads();
  float q=0.f;
  #pragma unroll
  for (int j=0;j<4;j++){ float d=cn[j]-muc; q+=d*d; }
  q=wave_sum(q);
  if(lane==0) red[w]=q;
  __syncthreads();
  float rsc=rsqrtf((red[0]+red[1]+red[2]+red[3])*(1.f/1024.f)+EPSV);
  float h[4];
  #pragma unroll
  for (int j=0;j<4;j++) h[j]=sigf(y[2][j])*tanhf((cn[j]-muc)*rsc*lnc_w[o0+j]+lnc_b[o0+j]);
  float4 hv; hv.x=h[0]; hv.y=h[1]; hv.z=h[2]; hv.w=h[3];
  float4 cv; cv.x=cn[0]; cv.y=cn[1]; cv.z=cn[2]; cv.w=cn[3];
  *(float4*)(h_out +(size_t)b*1024+o0) = hv;
  *(float4*)(ht_out+(size_t)b*LDT +o0) = hv;
  *(float4*)(ct_out+(size_t)b*LDT +o0) = cv;
}

extern "C" void kernel_launch(void* const* d_in, const int* in_sizes, int n_in,
                              void* d_out, int out_size, void* d_ws, size_t ws_size,
                              hipStream_t stream) {
  (void)in_sizes; (void)n_in; (void)out_size; (void)ws_size;
  const float* x         = (const float*)d_in[0];
  const float* h_total   = (const float*)d_in[1];
  const float* c_total   = (const float*)d_in[2];
  const float* hyp_w_ih  = (const float*)d_in[3];
  const float* hyp_w_hh  = (const float*)d_in[4];
  const float* hyp_lnh_w = (const float*)d_in[5];
  const float* hyp_lnh_b = (const float*)d_in[6];
  const float* hyp_lnc_w = (const float*)d_in[7];
  const float* hyp_lnc_b = (const float*)d_in[8];
  const float* w_ih      = (const float*)d_in[9];
  const float* w_hh      = (const float*)d_in[10];
  const float* lnh_w     = (const float*)d_in[11];
  const float* lnh_b     = (const float*)d_in[12];
  const float* lnc_w     = (const float*)d_in[13];
  const float* lnc_b     = (const float*)d_in[14];
  const float* sx_w0     = (const float*)d_in[15];
  const float* sx_b0     = (const float*)d_in[16];
  const float* sx_w1     = (const float*)d_in[17];
  const float* sh_w0     = (const float*)d_in[18];
  const float* sh_b0     = (const float*)d_in[19];
  const float* sh_w1     = (const float*)d_in[20];
  const float* bh_w0     = (const float*)d_in[21];
  const float* bh_w1     = (const float*)d_in[22];

  float* out    = (float*)d_out;
  float* h_out  = out;
  float* ht_out = out + (size_t)BB*1024;
  float* ct_out = ht_out + (size_t)BB*LDT;

  char* p = (char*)d_ws;
  float* lin = (float*)p;  p += (size_t)4096*1024*4;
  float* Wx  = (float*)p;  p += (size_t)4096*4096*4;
  float* Wh  = (float*)p;  p += (size_t)4096*4096*4;
  float* zx  = (float*)p;  p += (size_t)4096*128*4;
  float* zh  = (float*)p;  p += (size_t)4096*128*4;
  float* zb  = (float*)p;  p += (size_t)4096*128*4;
  u16* Hbig  = (u16*)p;    p += (size_t)4096*3072*2;
  u16* Wihb  = (u16*)p;    p += (size_t)4096*1536*2;
  u16* Whhb  = (u16*)p;    p += (size_t)4096*3072*2;
  u16* XHhyp = (u16*)p;    p += (size_t)4096*2304*2;   // [x split 1536 | h_hyper split 768]
  u16* Whyp  = (u16*)p;    p += (size_t)1024*2304*2;   // [w_ih split 1536 | w_hh split 768]

  // split-bf16 conversions (mode 0 = A side [hi|lo|hi], mode 1 = B side [hi|hi|lo])
  cvt_split<<<dim3(2,4096),64,0,stream>>>(x, 512, 512, XHhyp, 2304, 0);
  cvt_split<<<dim3(1,4096),64,0,stream>>>(h_total+1024, LDT, 256, XHhyp+1536, 2304, 0);
  cvt_split<<<dim3(4,4096),64,0,stream>>>(h_total, LDT, 1024, Hbig, 3072, 0);
  cvt_split<<<dim3(2,4096),64,0,stream>>>(w_ih, 512, 512, Wihb, 1536, 1);
  cvt_split<<<dim3(4,4096),64,0,stream>>>(w_hh, 1024, 1024, Whhb, 3072, 1);
  cvt_split<<<dim3(2,1024),64,0,stream>>>(hyp_w_ih, 512, 512, Whyp, 2304, 1);
  cvt_split<<<dim3(1,1024),64,0,stream>>>(hyp_w_hh, 256, 256, Whyp+1536, 2304, 1);

  // hyper linear (combined K'=2304): lin = x@hyp_w_ih.T + h_hyper@hyp_w_hh.T
  gemm_bf16nt<<<dim3(8,32),256,0,stream>>>(XHhyp,2304, Whyp,2304, lin,1024, 2304, 0);
  // main big GEMMs on the 256x256 8-phase kernel
  gemm256<<<dim3(16,16),512,0,stream>>>(XHhyp,2304, Wihb,1536, Wx,4096, 1536);
  gemm256<<<dim3(16,16),512,0,stream>>>(Hbig,3072, Whhb,3072, Wh,4096, 3072);

  hyper_cell<<<4096,256,0,stream>>>(lin, c_total, hyp_lnh_w, hyp_lnh_b, hyp_lnc_w, hyp_lnc_b, ht_out, ct_out);

  zproj<<<dim3(3,32),256,0,stream>>>(ht_out+1024, sx_w0, sh_w0, bh_w0, sx_b0, sh_b0, zx, zh, zb);

  scale_apply<<<dim3(64,64),256,0,stream>>>(Wx, Wh, zx, zh, zb, sx_w1, sh_w1, bh_w1, Wx);
  main_cell<<<4096,256,0,stream>>>(Wx, c_total, lnh_w, lnh_b, lnc_w, lnc_b, h_out, ht_out, ct_out);
}

// Round 8
// 427.433 us; speedup vs baseline: 2.4735x; 1.2118x over previous
//
#include <hip/hip_runtime.h>
#include <math.h>

typedef unsigned short u16;
typedef unsigned int u32;
typedef unsigned long long u64;
typedef __attribute__((ext_vector_type(4))) float vf4;
typedef __attribute__((ext_vector_type(8))) _Float16 f16x8;

#define EPSV 1e-5f
#define BB 4096
#define LDT 1280   // H + HH

__device__ __forceinline__ float sigf(float x){
  float e = expf(-fabsf(x));
  float r = 1.f/(1.f+e);
  return x>=0.f ? r : 1.f-r;
}

__device__ __forceinline__ float wave_sum(float v){
  #pragma unroll
  for (int m=32;m>0;m>>=1) v += __shfl_xor(v, m);
  return v;
}

#define AS1 __attribute__((address_space(1)))
#define AS3 __attribute__((address_space(3)))
__device__ __forceinline__ void gload_lds16(const u16* g, u16* l){
  __builtin_amdgcn_global_load_lds((const AS1 void*)g, (AS3 void*)l, 16, 0, 0);
}

// ---------------- fp32 -> fp16 conversion (plain, no split) ----------------
__global__ __launch_bounds__(64) void cvt_half(const float* __restrict__ in, int ld_in, int K,
                                               u16* __restrict__ out, int ld_out)
{
  int row = blockIdx.y;
  int c4 = (blockIdx.x*64 + threadIdx.x)*4;
  if (c4 >= K) return;
  float4 v = *(const float4*)(in + (size_t)row*ld_in + c4);
  float vv[4] = {v.x, v.y, v.z, v.w};
  u64 pk=0;
  #pragma unroll
  for (int j=0;j<4;j++){
    _Float16 h = (_Float16)vv[j];
    pk |= (u64)__builtin_bit_cast(u16, h) << (16*j);
  }
  *(u64*)(out + (size_t)row*ld_out + c4) = pk;
}

// ================= 256x256 8-phase fp16 MFMA NT GEMM (T2+T3+T4+T5) =================
// 512 threads = 8 waves (2M x 4N), BK=64, double-buffered 128KiB LDS.
// m201 rhythm: ds_reads issued BEFORE the leading barrier; A-frags register-
// pipelined one phase ahead; all 8 staging loads at phase 0; per-wave vmcnt(0)
// drain at end of phase 3 (own loads ~3.5 phases old) + barrier.
template<int P>
__device__ __forceinline__ void load_afrag(const u16* Ab, int wm, int lm, int kg, f16x8 af[2][2]){
  #pragma unroll
  for (int fl=0; fl<2; fl++)
    #pragma unroll
    for (int kk=0; kk<2; kk++){
      int row = wm*128 + (P*2+fl)*16 + lm;
      int sl = (kk*4+kg) ^ (row&7);
      af[fl][kk] = *(const f16x8*)(Ab + row*64 + sl*8);
    }
}

template<int P>
__device__ __forceinline__ void mfma_phase(vf4 acc[8][4], const f16x8 af[2][2], const f16x8 bf[4][2]){
  __builtin_amdgcn_s_setprio(1);
  #pragma unroll
  for (int fl=0; fl<2; fl++)
    #pragma unroll
    for (int j=0; j<4; j++)
      #pragma unroll
      for (int kk=0; kk<2; kk++)
        acc[P*2+fl][j] = __builtin_amdgcn_mfma_f32_16x16x32_f16(af[fl][kk], bf[j][kk], acc[P*2+fl][j], 0, 0, 0);
  __builtin_amdgcn_s_setprio(0);
}

__global__ __launch_bounds__(512, 2) void gemm256(
    const u16* __restrict__ A, int lda,
    const u16* __restrict__ B, int ldb,
    float* __restrict__ C, int ldc, int K)
{
  __shared__ u16 As[2][256*64];
  __shared__ u16 Bs[2][256*64];
  const int tid = threadIdx.x;
  const int lane = tid & 63;
  const int wid = tid >> 6;
  const int wm = wid >> 2, wn = wid & 3;
  const int m0 = blockIdx.y*256, n0 = blockIdx.x*256;
  const int kg = lane>>4, lm = lane&15;

  vf4 acc[8][4];
  #pragma unroll
  for (int i=0;i<8;i++)
    #pragma unroll
    for (int j=0;j<4;j++) acc[i][j] = (vf4){0.f,0.f,0.f,0.f};

  // staging map: 2048 16B-chunks per matrix per K-tile; thread covers chunk q*512+tid.
  // chunk c: row=c>>3, phys slot=c&7; source col16 = slot ^ (row&7) (inverse swizzle).
  const u16* gA[4]; const u16* gB[4]; int ldsOff[4];
  #pragma unroll
  for (int q=0;q<4;q++){
    int c = q*512 + tid;
    int row = c>>3, slot = c&7;
    int scol = slot ^ (row&7);
    gA[q] = A + (size_t)(m0+row)*lda + scol*8;
    gB[q] = B + (size_t)(n0+row)*ldb + scol*8;
    ldsOff[q] = (q*512 + wid*64)*8;   // wave-uniform dest base (lane*16B appended by HW)
  }

  const int NT = K>>6;
  // prologue: stage tile 0 into buf 0
  #pragma unroll
  for (int q=0;q<4;q++) gload_lds16(gA[q], &As[0][ldsOff[q]]);
  #pragma unroll
  for (int q=0;q<4;q++) gload_lds16(gB[q], &Bs[0][ldsOff[q]]);
  asm volatile("s_waitcnt vmcnt(0)" ::: "memory");
  __builtin_amdgcn_s_barrier();

  f16x8 afA[2][2], afB[2][2], bfrag[4][2];

  for (int t=0; t<NT; ++t){
    const int cur = t&1, nxt = cur^1;
    const u16* Ab = As[cur];
    const u16* Bb = Bs[cur];

    // ---- phase 0: pre-barrier reads (af0, af1, all bfrag) + stage tile t+1 ----
    load_afrag<0>(Ab, wm, lm, kg, afA);
    #pragma unroll
    for (int j=0;j<4;j++)
      #pragma unroll
      for (int kk=0;kk<2;kk++){
        int row = wn*64 + j*16 + lm;
        int sl = (kk*4+kg) ^ (row&7);
        bfrag[j][kk] = *(const f16x8*)(Bb + row*64 + sl*8);
      }
    load_afrag<1>(Ab, wm, lm, kg, afB);
    if (t+1 < NT){
      const int kb = (t+1)<<6;
      #pragma unroll
      for (int q=0;q<4;q++) gload_lds16(gA[q]+kb, &As[nxt][ldsOff[q]]);
      #pragma unroll
      for (int q=0;q<4;q++) gload_lds16(gB[q]+kb, &Bs[nxt][ldsOff[q]]);
    }
    __builtin_amdgcn_sched_barrier(0);
    __builtin_amdgcn_s_barrier();
    mfma_phase<0>(acc, afA, bfrag);
    __builtin_amdgcn_s_barrier();

    // ---- phase 1: read af2 (for phase 2), compute af1 ----
    load_afrag<2>(Ab, wm, lm, kg, afA);
    __builtin_amdgcn_sched_barrier(0);
    __builtin_amdgcn_s_barrier();
    mfma_phase<1>(acc, afB, bfrag);
    __builtin_amdgcn_s_barrier();

    // ---- phase 2: read af3, compute af2 ----
    load_afrag<3>(Ab, wm, lm, kg, afB);
    __builtin_amdgcn_sched_barrier(0);
    __builtin_amdgcn_s_barrier();
    mfma_phase<2>(acc, afA, bfrag);
    __builtin_amdgcn_s_barrier();

    // ---- phase 3: compute af3, then drain own staged loads + barrier ----
    __builtin_amdgcn_sched_barrier(0);
    __builtin_amdgcn_s_barrier();
    mfma_phase<3>(acc, afB, bfrag);
    asm volatile("s_waitcnt vmcnt(0)" ::: "memory");   // own 8 loads, issued ~3.5 phases ago
    __builtin_amdgcn_s_barrier();                       // => all waves' tile t+1 landed
  }

  // C/D layout (m89-verified): col = lane&15, row = (lane>>4)*4 + reg
  #pragma unroll
  for (int f=0; f<8; f++){
    int rb = m0 + wm*128 + f*16 + kg*4;
    #pragma unroll
    for (int j=0; j<4; j++){
      int cc = n0 + wn*64 + j*16 + lm;
      #pragma unroll
      for (int r=0; r<4; r++)
        C[(size_t)(rb+r)*ldc + cc] = acc[f][j][r];
    }
  }
}

// ---------------- 128x128 fp16 MFMA NT GEMM (m97 structure) ----------------
__global__ __launch_bounds__(256) void gemm_f16nt(
    const u16* __restrict__ A, int lda,
    const u16* __restrict__ B, int ldb,
    float* __restrict__ C, int ldc,
    int K, int accflag)
{
  __shared__ u16 As[128*32];
  __shared__ u16 Bs[128*32];
  const int tid = threadIdx.x;
  const int lane = tid & 63;
  const int w = tid >> 6;
  const int wr = w >> 1, wc = w & 1;
  const int m0 = blockIdx.y*128, n0 = blockIdx.x*128;

  vf4 acc[4][4];
  #pragma unroll
  for (int i=0;i<4;i++)
    #pragma unroll
    for (int j=0;j<4;j++) acc[i][j] = (vf4){0.f,0.f,0.f,0.f};

  const int c0i = w*128 + lane;
  const int c1i = c0i + 64;
  const int r0i = c0i>>2, s0i = (c0i&3) ^ ((r0i>>1)&3);
  const int r1i = c1i>>2, s1i = (c1i&3) ^ ((r1i>>1)&3);
  const u16* gA0 = A + (size_t)(m0+r0i)*lda + s0i*8;
  const u16* gA1 = A + (size_t)(m0+r1i)*lda + s1i*8;
  const u16* gB0 = B + (size_t)(n0+r0i)*ldb + s0i*8;
  const u16* gB1 = B + (size_t)(n0+r1i)*ldb + s1i*8;
  u16* lA0 = As + w*1024;
  u16* lA1 = As + w*1024 + 512;
  u16* lB0 = Bs + w*1024;
  u16* lB1 = Bs + w*1024 + 512;

  const int kg = lane>>4, lm = lane&15;

  for (int k0=0; k0<K; k0+=32){
    __syncthreads();
    gload_lds16(gA0 + k0, lA0);
    gload_lds16(gA1 + k0, lA1);
    gload_lds16(gB0 + k0, lB0);
    gload_lds16(gB1 + k0, lB1);
    __syncthreads();
    f16x8 af[4], bfr[4];
    #pragma unroll
    for (int i=0;i<4;i++){
      int ra = wr*64 + i*16 + lm;
      int sa = kg ^ ((ra>>1)&3);
      af[i] = *(const f16x8*)(As + ra*32 + sa*8);
      int rb = wc*64 + i*16 + lm;
      int sb = kg ^ ((rb>>1)&3);
      bfr[i] = *(const f16x8*)(Bs + rb*32 + sb*8);
    }
    #pragma unroll
    for (int i=0;i<4;i++)
      #pragma unroll
      for (int j=0;j<4;j++)
        acc[i][j] = __builtin_amdgcn_mfma_f32_16x16x32_f16(af[i], bfr[j], acc[i][j], 0, 0, 0);
  }

  const int lhi = lane>>4;
  #pragma unroll
  for (int i=0;i<4;i++){
    int rbase = m0 + wr*64 + i*16 + lhi*4;
    #pragma unroll
    for (int j=0;j<4;j++){
      int cc = n0 + wc*64 + j*16 + lm;
      #pragma unroll
      for (int r=0;r<4;r++){
        float v = acc[i][j][r];
        float* pC = C + (size_t)(rbase+r)*ldc + cc;
        if (accflag) v += *pC;
        *pC = v;
      }
    }
  }
}

// ---------------- hyper LSTM cell ----------------
__global__ __launch_bounds__(256) void hyper_cell(
    const float* __restrict__ lin, const float* __restrict__ c_in,
    const float* __restrict__ lnh_w, const float* __restrict__ lnh_b,
    const float* __restrict__ lnc_w, const float* __restrict__ lnc_b,
    float* __restrict__ ht_out, float* __restrict__ ct_out)
{
  int b=blockIdx.x, tid=threadIdx.x, lane=tid&63, w=tid>>6;
  __shared__ float ly[1024];
  __shared__ float red[4];
  float4 t = *(const float4*)(lin + (size_t)b*1024 + tid*4);
  float v[4]={t.x,t.y,t.z,t.w};
  float s = wave_sum(v[0]+v[1]+v[2]+v[3]);
  float mu = s*(1.f/256.f);
  float q=0.f;
  #pragma unroll
  for (int j=0;j<4;j++){ float d=v[j]-mu; q+=d*d; }
  q = wave_sum(q);
  float rs = rsqrtf(q*(1.f/256.f)+EPSV);
  int base = tid*4;
  #pragma unroll
  for (int j=0;j<4;j++) ly[base+j] = (v[j]-mu)*rs*lnh_w[base+j]+lnh_b[base+j];
  __syncthreads();
  float ig=ly[tid], fg=ly[256+tid], og=ly[512+tid], cc=ly[768+tid];
  float co = c_in[(size_t)b*LDT + 1024 + tid];
  float cn = sigf(fg+1.f)*co + sigf(ig)*tanhf(cc);
  float s2 = wave_sum(cn);
  if(lane==0) red[w]=s2;
  __syncthreads();
  float mu2=(red[0]+red[1]+red[2]+red[3])*(1.f/256.f);
  __syncthreads();
  float d = cn-mu2;
  float q2 = wave_sum(d*d);
  if(lane==0) red[w]=q2;
  __syncthreads();
  float rs2 = rsqrtf((red[0]+red[1]+red[2]+red[3])*(1.f/256.f)+EPSV);
  float hh = sigf(og)*tanhf(d*rs2*lnc_w[tid]+lnc_b[tid]);
  ht_out[(size_t)b*LDT+1024+tid]=hh;
  ct_out[(size_t)b*LDT+1024+tid]=cn;
}

// ---------------- scale apply (z from zcat with ld=384, b0 folded in) ----------------
#define EST 68
__device__ __forceinline__ void stage_dot(
    const float* __restrict__ zp, const float* __restrict__ wp, const float* __restrict__ bias,
    int r0, int gc0, int g, int tid, int tx, int ty,
    float (&acc)[4][4], float* Zs, float* Ws)
{
  const int lr = tid>>2;
  const int le4 = (tid&3)<<2;
  float4 zv0 = *(const float4*)(zp + (size_t)(r0+lr)*384 + g*32 + le4);
  float4 zv1 = *(const float4*)(zp + (size_t)(r0+lr)*384 + g*32 + le4 + 16);
  if (bias){
    zv0.x += bias[g*32+le4+0]; zv0.y += bias[g*32+le4+1];
    zv0.z += bias[g*32+le4+2]; zv0.w += bias[g*32+le4+3];
    zv1.x += bias[g*32+le4+16]; zv1.y += bias[g*32+le4+17];
    zv1.z += bias[g*32+le4+18]; zv1.w += bias[g*32+le4+19];
  }
  float4 wv0 = *(const float4*)(wp + ((size_t)(g*1024 + gc0 + lr))*32 + le4);
  float4 wv1 = *(const float4*)(wp + ((size_t)(g*1024 + gc0 + lr))*32 + le4 + 16);
  __syncthreads();
  Zs[(le4+0)*EST+lr]=zv0.x; Zs[(le4+1)*EST+lr]=zv0.y; Zs[(le4+2)*EST+lr]=zv0.z; Zs[(le4+3)*EST+lr]=zv0.w;
  Zs[(le4+16)*EST+lr]=zv1.x; Zs[(le4+17)*EST+lr]=zv1.y; Zs[(le4+18)*EST+lr]=zv1.z; Zs[(le4+19)*EST+lr]=zv1.w;
  Ws[(le4+0)*EST+lr]=wv0.x; Ws[(le4+1)*EST+lr]=wv0.y; Ws[(le4+2)*EST+lr]=wv0.z; Ws[(le4+3)*EST+lr]=wv0.w;
  Ws[(le4+16)*EST+lr]=wv1.x; Ws[(le4+17)*EST+lr]=wv1.y; Ws[(le4+18)*EST+lr]=wv1.z; Ws[(le4+19)*EST+lr]=wv1.w;
  __syncthreads();
  #pragma unroll
  for (int i=0;i<4;i++)
    #pragma unroll
    for (int j=0;j<4;j++) acc[i][j]=0.f;
  #pragma unroll
  for (int e=0;e<32;e++){
    float4 av = *(const float4*)&Zs[e*EST + ty*4];
    float4 bv = *(const float4*)&Ws[e*EST + tx*4];
    float a[4]={av.x,av.y,av.z,av.w}, b[4]={bv.x,bv.y,bv.z,bv.w};
    #pragma unroll
    for (int i=0;i<4;i++)
      #pragma unroll
      for (int j=0;j<4;j++) acc[i][j]+=a[i]*b[j];
  }
}

__global__ __launch_bounds__(256) void scale_apply(
  const float* __restrict__ Wx, const float* __restrict__ Wh,
  const float* __restrict__ zcat,
  const float* __restrict__ b0x, const float* __restrict__ b0h,
  const float* __restrict__ w1x, const float* __restrict__ w1h, const float* __restrict__ w1b,
  float* __restrict__ glin)
{
  __shared__ float Zs[32*EST], Ws[32*EST];
  int tid=threadIdx.x;
  int c0=blockIdx.x*64, r0=blockIdx.y*64;
  int g=c0>>10, gc0=c0&1023;
  int tx=tid&15, ty=tid>>4;
  float acc[4][4], gval[4][4];

  stage_dot(zcat,     w1x, b0x, r0, gc0, g, tid, tx, ty, acc, Zs, Ws);
  #pragma unroll
  for (int i=0;i<4;i++){
    float4 wv = *(const float4*)(Wx + (size_t)(r0+ty*4+i)*4096 + c0 + tx*4);
    gval[i][0]=acc[i][0]*wv.x; gval[i][1]=acc[i][1]*wv.y;
    gval[i][2]=acc[i][2]*wv.z; gval[i][3]=acc[i][3]*wv.w;
  }
  stage_dot(zcat+128, w1h, b0h, r0, gc0, g, tid, tx, ty, acc, Zs, Ws);
  #pragma unroll
  for (int i=0;i<4;i++){
    float4 wv = *(const float4*)(Wh + (size_t)(r0+ty*4+i)*4096 + c0 + tx*4);
    gval[i][0]+=acc[i][0]*wv.x; gval[i][1]+=acc[i][1]*wv.y;
    gval[i][2]+=acc[i][2]*wv.z; gval[i][3]+=acc[i][3]*wv.w;
  }
  stage_dot(zcat+256, w1b, nullptr, r0, gc0, g, tid, tx, ty, acc, Zs, Ws);
  #pragma unroll
  for (int i=0;i<4;i++){
    float4 v;
    v.x=gval[i][0]+acc[i][0]; v.y=gval[i][1]+acc[i][1];
    v.z=gval[i][2]+acc[i][2]; v.w=gval[i][3]+acc[i][3];
    *(float4*)(glin + (size_t)(r0+ty*4+i)*4096 + c0 + tx*4) = v;
  }
}

// ---------------- main LSTM cell ----------------
__global__ __launch_bounds__(256) void main_cell(
    const float* __restrict__ glin, const float* __restrict__ c_in,
    const float* __restrict__ lnh_w, const float* __restrict__ lnh_b,
    const float* __restrict__ lnc_w, const float* __restrict__ lnc_b,
    float* __restrict__ h_out, float* __restrict__ ht_out, float* __restrict__ ct_out)
{
  int b=blockIdx.x, tid=threadIdx.x, lane=tid&63, w=tid>>6;
  __shared__ float red[16];
  float v[4][4];
  #pragma unroll
  for (int g=0;g<4;g++){
    float4 t = *(const float4*)(glin + (size_t)b*4096 + g*1024 + tid*4);
    v[g][0]=t.x; v[g][1]=t.y; v[g][2]=t.z; v[g][3]=t.w;
  }
  float mu[4], rs[4];
  #pragma unroll
  for (int g=0;g<4;g++){
    float s = wave_sum(v[g][0]+v[g][1]+v[g][2]+v[g][3]);
    if(lane==0) red[g*4+w]=s;
  }
  __syncthreads();
  #pragma unroll
  for (int g=0;g<4;g++) mu[g]=(red[g*4]+red[g*4+1]+red[g*4+2]+red[g*4+3])*(1.f/1024.f);
  __syncthreads();
  #pragma unroll
  for (int g=0;g<4;g++){
    float q=0.f;
    #pragma unroll
    for (int j=0;j<4;j++){ float d=v[g][j]-mu[g]; q+=d*d; }
    q = wave_sum(q);
    if(lane==0) red[g*4+w]=q;
  }
  __syncthreads();
  #pragma unroll
  for (int g=0;g<4;g++) rs[g]=rsqrtf((red[g*4]+red[g*4+1]+red[g*4+2]+red[g*4+3])*(1.f/1024.f)+EPSV);
  int o0=tid*4;
  float y[4][4];
  #pragma unroll
  for (int g=0;g<4;g++)
    #pragma unroll
    for (int j=0;j<4;j++){
      int idx=g*1024+o0+j;
      y[g][j]=(v[g][j]-mu[g])*rs[g]*lnh_w[idx]+lnh_b[idx];
    }
  float4 ct = *(const float4*)(c_in + (size_t)b*LDT + o0);
  float co[4]={ct.x,ct.y,ct.z,ct.w};
  float cn[4];
  #pragma unroll
  for (int j=0;j<4;j++) cn[j]=sigf(y[1][j]+1.f)*co[j] + sigf(y[0][j])*tanhf(y[3][j]);
  float s = wave_sum(cn[0]+cn[1]+cn[2]+cn[3]);
  __syncthreads();
  if(lane==0) red[w]=s;
  __syncthreads();
  float muc=(red[0]+red[1]+red[2]+red[3])*(1.f/1024.f);
  __syncthreads();
  float q=0.f;
  #pragma unroll
  for (int j=0;j<4;j++){ float d=cn[j]-muc; q+=d*d; }
  q=wave_sum(q);
  if(lane==0) red[w]=q;
  __syncthreads();
  float rsc=rsqrtf((red[0]+red[1]+red[2]+red[3])*(1.f/1024.f)+EPSV);
  float h[4];
  #pragma unroll
  for (int j=0;j<4;j++) h[j]=sigf(y[2][j])*tanhf((cn[j]-muc)*rsc*lnc_w[o0+j]+lnc_b[o0+j]);
  float4 hv; hv.x=h[0]; hv.y=h[1]; hv.z=h[2]; hv.w=h[3];
  float4 cv; cv.x=cn[0]; cv.y=cn[1]; cv.z=cn[2]; cv.w=cn[3];
  *(float4*)(h_out +(size_t)b*1024+o0) = hv;
  *(float4*)(ht_out+(size_t)b*LDT +o0) = hv;
  *(float4*)(ct_out+(size_t)b*LDT +o0) = cv;
}

extern "C" void kernel_launch(void* const* d_in, const int* in_sizes, int n_in,
                              void* d_out, int out_size, void* d_ws, size_t ws_size,
                              hipStream_t stream) {
  (void)in_sizes; (void)n_in; (void)out_size; (void)ws_size;
  const float* x         = (const float*)d_in[0];
  const float* h_total   = (const float*)d_in[1];
  const float* c_total   = (const float*)d_in[2];
  const float* hyp_w_ih  = (const float*)d_in[3];
  const float* hyp_w_hh  = (const float*)d_in[4];
  const float* hyp_lnh_w = (const float*)d_in[5];
  const float* hyp_lnh_b = (const float*)d_in[6];
  const float* hyp_lnc_w = (const float*)d_in[7];
  const float* hyp_lnc_b = (const float*)d_in[8];
  const float* w_ih      = (const float*)d_in[9];
  const float* w_hh      = (const float*)d_in[10];
  const float* lnh_w     = (const float*)d_in[11];
  const float* lnh_b     = (const float*)d_in[12];
  const float* lnc_w     = (const float*)d_in[13];
  const float* lnc_b     = (const float*)d_in[14];
  const float* sx_w0     = (const float*)d_in[15];
  const float* sx_b0     = (const float*)d_in[16];
  const float* sx_w1     = (const float*)d_in[17];
  const float* sh_w0     = (const float*)d_in[18];
  const float* sh_b0     = (const float*)d_in[19];
  const float* sh_w1     = (const float*)d_in[20];
  const float* bh_w0     = (const float*)d_in[21];
  const float* bh_w1     = (const float*)d_in[22];

  float* out    = (float*)d_out;
  float* h_out  = out;
  float* ht_out = out + (size_t)BB*1024;
  float* ct_out = ht_out + (size_t)BB*LDT;

  char* p = (char*)d_ws;
  float* lin   = (float*)p; p += (size_t)4096*1024*4;
  float* Wx    = (float*)p; p += (size_t)4096*4096*4;
  float* Wh    = (float*)p; p += (size_t)4096*4096*4;
  float* zcat  = (float*)p; p += (size_t)4096*384*4;
  u16* Hbig    = (u16*)p;   p += (size_t)4096*1024*2;  // h fp16
  u16* Wihb    = (u16*)p;   p += (size_t)4096*512*2;
  u16* Whhb    = (u16*)p;   p += (size_t)4096*1024*2;
  u16* XHhyp   = (u16*)p;   p += (size_t)4096*768*2;   // [x fp16 512 | h_hyper fp16 256]
  u16* Whyp    = (u16*)p;   p += (size_t)1024*768*2;   // [hyp_w_ih 512 | hyp_w_hh 256]
  u16* Hhyp16  = (u16*)p;   p += (size_t)4096*256*2;   // NEW h_hyper fp16
  u16* Zw      = (u16*)p;   p += (size_t)384*256*2;    // [sx_w0 | sh_w0 | bh_w0] fp16

  // fp16 conversions
  cvt_half<<<dim3(2,4096),64,0,stream>>>(x, 512, 512, XHhyp, 768);
  cvt_half<<<dim3(1,4096),64,0,stream>>>(h_total+1024, LDT, 256, XHhyp+512, 768);
  cvt_half<<<dim3(4,4096),64,0,stream>>>(h_total, LDT, 1024, Hbig, 1024);
  cvt_half<<<dim3(2,4096),64,0,stream>>>(w_ih, 512, 512, Wihb, 512);
  cvt_half<<<dim3(4,4096),64,0,stream>>>(w_hh, 1024, 1024, Whhb, 1024);
  cvt_half<<<dim3(2,1024),64,0,stream>>>(hyp_w_ih, 512, 512, Whyp, 768);
  cvt_half<<<dim3(1,1024),64,0,stream>>>(hyp_w_hh, 256, 256, Whyp+512, 768);
  cvt_half<<<dim3(1,128),64,0,stream>>>(sx_w0, 256, 256, Zw, 256);
  cvt_half<<<dim3(1,128),64,0,stream>>>(sh_w0, 256, 256, Zw+(size_t)128*256, 256);
  cvt_half<<<dim3(1,128),64,0,stream>>>(bh_w0, 256, 256, Zw+(size_t)256*256, 256);

  // hyper linear (K=768): lin = x@hyp_w_ih.T + h_hyper@hyp_w_hh.T
  gemm_f16nt<<<dim3(8,32),256,0,stream>>>(XHhyp,768, Whyp,768, lin,1024, 768, 0);
  // main big GEMMs (plain fp16, real K)
  gemm256<<<dim3(16,16),512,0,stream>>>(XHhyp,768, Wihb,512, Wx,4096, 512);
  gemm256<<<dim3(16,16),512,0,stream>>>(Hbig,1024, Whhb,1024, Wh,4096, 1024);

  hyper_cell<<<4096,256,0,stream>>>(lin, c_total, hyp_lnh_w, hyp_lnh_b, hyp_lnc_w, hyp_lnc_b, ht_out, ct_out);

  // z projections as one batched fp16 GEMM: zcat[4096,384] = h_hyper_new @ [w0x|w0h|w0b].T
  cvt_half<<<dim3(1,4096),64,0,stream>>>(ht_out+1024, LDT, 256, Hhyp16, 256);
  gemm_f16nt<<<dim3(3,32),256,0,stream>>>(Hhyp16,256, Zw,256, zcat,384, 256, 0);

  scale_apply<<<dim3(64,64),256,0,stream>>>(Wx, Wh, zcat, sx_b0, sh_b0, sx_w1, sh_w1, bh_w1, Wx);
  main_cell<<<4096,256,0,stream>>>(Wx, c_total, lnh_w, lnh_b, lnc_w, lnc_b, h_out, ht_out, ct_out);
}

// Round 9
// 352.654 us; speedup vs baseline: 2.9980x; 1.2120x over previous
//
#include <hip/hip_runtime.h>
#include <math.h>

typedef unsigned short u16;
typedef unsigned int u32;
typedef unsigned long long u64;
typedef __attribute__((ext_vector_type(4))) float vf4;
typedef __attribute__((ext_vector_type(8))) _Float16 f16x8;

#define EPSV 1e-5f
#define BB 4096
#define LDT 1280   // H + HH

__device__ __forceinline__ float sigf(float x){
  float e = expf(-fabsf(x));
  float r = 1.f/(1.f+e);
  return x>=0.f ? r : 1.f-r;
}

__device__ __forceinline__ float wave_sum(float v){
  #pragma unroll
  for (int m=32;m>0;m>>=1) v += __shfl_xor(v, m);
  return v;
}

#define AS1 __attribute__((address_space(1)))
#define AS3 __attribute__((address_space(3)))
__device__ __forceinline__ void gload_lds16(const u16* g, u16* l){
  __builtin_amdgcn_global_load_lds((const AS1 void*)g, (AS3 void*)l, 16, 0, 0);
}

__device__ __forceinline__ u64 pack_half4(float4 v){
  u64 pk=0;
  float vv[4] = {v.x, v.y, v.z, v.w};
  #pragma unroll
  for (int j=0;j<4;j++){
    _Float16 h = (_Float16)vv[j];
    pk |= (u64)__builtin_bit_cast(u16, h) << (16*j);
  }
  return pk;
}

// ---------------- merged fp32->fp16 conversions ----------------
// activations: virtual row of 1792 = [x 512 | h 1024 | h_hyper 256]
__global__ __launch_bounds__(64) void cvt_acts(const float* __restrict__ x,
                                               const float* __restrict__ h_total,
                                               u16* __restrict__ XHhyp, u16* __restrict__ Hbig)
{
  int row = blockIdx.y;
  int c4 = (blockIdx.x*64 + threadIdx.x)*4;
  if (c4 >= 1792) return;
  const float* src; u16* dst;
  if (c4 < 512){ src = x + (size_t)row*512 + c4;                 dst = XHhyp + (size_t)row*768 + c4; }
  else if (c4 < 1536){ src = h_total + (size_t)row*LDT + (c4-512); dst = Hbig + (size_t)row*1024 + (c4-512); }
  else { src = h_total + (size_t)row*LDT + 1024 + (c4-1536);     dst = XHhyp + (size_t)row*768 + 512 + (c4-1536); }
  *(u64*)dst = pack_half4(*(const float4*)src);
}

// main weights: virtual row 1536 = [w_ih 512 | w_hh 1024], 4096 rows
__global__ __launch_bounds__(64) void cvt_wmain(const float* __restrict__ w_ih,
                                                const float* __restrict__ w_hh,
                                                u16* __restrict__ Wihb, u16* __restrict__ Whhb)
{
  int row = blockIdx.y;
  int c4 = (blockIdx.x*64 + threadIdx.x)*4;
  if (c4 >= 1536) return;
  const float* src; u16* dst;
  if (c4 < 512){ src = w_ih + (size_t)row*512 + c4;  dst = Wihb + (size_t)row*512 + c4; }
  else { src = w_hh + (size_t)row*1024 + (c4-512);   dst = Whhb + (size_t)row*1024 + (c4-512); }
  *(u64*)dst = pack_half4(*(const float4*)src);
}

// hyper weights: virtual row 768 = [hyp_w_ih 512 | hyp_w_hh 256], 1024 rows -> Whyp [1024][768]
__global__ __launch_bounds__(64) void cvt_whyp(const float* __restrict__ wih,
                                               const float* __restrict__ whh,
                                               u16* __restrict__ Whyp)
{
  int row = blockIdx.y;
  int c4 = (blockIdx.x*64 + threadIdx.x)*4;
  if (c4 >= 768) return;
  const float* src = (c4 < 512) ? (wih + (size_t)row*512 + c4) : (whh + (size_t)row*256 + (c4-512));
  *(u64*)(Whyp + (size_t)row*768 + c4) = pack_half4(*(const float4*)src);
}

// z-projection weights: 384 rows of 256 = [sx_w0 128 | sh_w0 128 | bh_w0 128]
__global__ __launch_bounds__(64) void cvt_zw(const float* __restrict__ w0x,
                                             const float* __restrict__ w0h,
                                             const float* __restrict__ w0b,
                                             u16* __restrict__ Zw)
{
  int row = blockIdx.y;
  int c4 = threadIdx.x*4;
  const float* src = (row<128) ? (w0x + (size_t)row*256) : (row<256 ? (w0h + (size_t)(row-128)*256) : (w0b + (size_t)(row-256)*256));
  *(u64*)(Zw + (size_t)row*256 + c4) = pack_half4(*(const float4*)(src + c4));
}

// w1 tensors flat: 3 x 131072 floats -> w1cat16 [3][4096][32]
__global__ __launch_bounds__(256) void cvt_w1(const float* __restrict__ w1x,
                                              const float* __restrict__ w1h,
                                              const float* __restrict__ w1b,
                                              u16* __restrict__ w1cat16)
{
  int i4 = (blockIdx.x*256 + threadIdx.x)*4;   // < 393216
  int t = i4 >> 17;           // /131072
  int off = i4 & 131071;
  const float* src = (t==0) ? w1x : (t==1 ? w1h : w1b);
  *(u64*)(w1cat16 + i4) = pack_half4(*(const float4*)(src + off));
}

// ================= 256x256 8-phase fp16 MFMA NT GEMM (T2+T3+T4+T5) =================
template<int P>
__device__ __forceinline__ void load_afrag(const u16* Ab, int wm, int lm, int kg, f16x8 af[2][2]){
  #pragma unroll
  for (int fl=0; fl<2; fl++)
    #pragma unroll
    for (int kk=0; kk<2; kk++){
      int row = wm*128 + (P*2+fl)*16 + lm;
      int sl = (kk*4+kg) ^ (row&7);
      af[fl][kk] = *(const f16x8*)(Ab + row*64 + sl*8);
    }
}

template<int P>
__device__ __forceinline__ void mfma_phase(vf4 acc[8][4], const f16x8 af[2][2], const f16x8 bf[4][2]){
  __builtin_amdgcn_s_setprio(1);
  #pragma unroll
  for (int fl=0; fl<2; fl++)
    #pragma unroll
    for (int j=0; j<4; j++)
      #pragma unroll
      for (int kk=0; kk<2; kk++)
        acc[P*2+fl][j] = __builtin_amdgcn_mfma_f32_16x16x32_f16(af[fl][kk], bf[j][kk], acc[P*2+fl][j], 0, 0, 0);
  __builtin_amdgcn_s_setprio(0);
}

__global__ __launch_bounds__(512, 2) void gemm256(
    const u16* __restrict__ A, int lda,
    const u16* __restrict__ B, int ldb,
    float* __restrict__ C, int ldc, int K)
{
  __shared__ u16 As[2][256*64];
  __shared__ u16 Bs[2][256*64];
  const int tid = threadIdx.x;
  const int lane = tid & 63;
  const int wid = tid >> 6;
  const int wm = wid >> 2, wn = wid & 3;
  const int m0 = blockIdx.y*256, n0 = blockIdx.x*256;
  const int kg = lane>>4, lm = lane&15;

  vf4 acc[8][4];
  #pragma unroll
  for (int i=0;i<8;i++)
    #pragma unroll
    for (int j=0;j<4;j++) acc[i][j] = (vf4){0.f,0.f,0.f,0.f};

  const u16* gA[4]; const u16* gB[4]; int ldsOff[4];
  #pragma unroll
  for (int q=0;q<4;q++){
    int c = q*512 + tid;
    int row = c>>3, slot = c&7;
    int scol = slot ^ (row&7);
    gA[q] = A + (size_t)(m0+row)*lda + scol*8;
    gB[q] = B + (size_t)(n0+row)*ldb + scol*8;
    ldsOff[q] = (q*512 + wid*64)*8;
  }

  const int NT = K>>6;
  #pragma unroll
  for (int q=0;q<4;q++) gload_lds16(gA[q], &As[0][ldsOff[q]]);
  #pragma unroll
  for (int q=0;q<4;q++) gload_lds16(gB[q], &Bs[0][ldsOff[q]]);
  asm volatile("s_waitcnt vmcnt(0)" ::: "memory");
  __builtin_amdgcn_s_barrier();

  f16x8 afA[2][2], afB[2][2], bfrag[4][2];

  for (int t=0; t<NT; ++t){
    const int cur = t&1, nxt = cur^1;
    const u16* Ab = As[cur];
    const u16* Bb = Bs[cur];

    load_afrag<0>(Ab, wm, lm, kg, afA);
    #pragma unroll
    for (int j=0;j<4;j++)
      #pragma unroll
      for (int kk=0;kk<2;kk++){
        int row = wn*64 + j*16 + lm;
        int sl = (kk*4+kg) ^ (row&7);
        bfrag[j][kk] = *(const f16x8*)(Bb + row*64 + sl*8);
      }
    load_afrag<1>(Ab, wm, lm, kg, afB);
    if (t+1 < NT){
      const int kb = (t+1)<<6;
      #pragma unroll
      for (int q=0;q<4;q++) gload_lds16(gA[q]+kb, &As[nxt][ldsOff[q]]);
      #pragma unroll
      for (int q=0;q<4;q++) gload_lds16(gB[q]+kb, &Bs[nxt][ldsOff[q]]);
    }
    __builtin_amdgcn_sched_barrier(0);
    __builtin_amdgcn_s_barrier();
    mfma_phase<0>(acc, afA, bfrag);
    __builtin_amdgcn_s_barrier();

    load_afrag<2>(Ab, wm, lm, kg, afA);
    __builtin_amdgcn_sched_barrier(0);
    __builtin_amdgcn_s_barrier();
    mfma_phase<1>(acc, afB, bfrag);
    __builtin_amdgcn_s_barrier();

    load_afrag<3>(Ab, wm, lm, kg, afB);
    __builtin_amdgcn_sched_barrier(0);
    __builtin_amdgcn_s_barrier();
    mfma_phase<2>(acc, afA, bfrag);
    __builtin_amdgcn_s_barrier();

    __builtin_amdgcn_sched_barrier(0);
    __builtin_amdgcn_s_barrier();
    mfma_phase<3>(acc, afB, bfrag);
    asm volatile("s_waitcnt vmcnt(0)" ::: "memory");
    __builtin_amdgcn_s_barrier();
  }

  #pragma unroll
  for (int f=0; f<8; f++){
    int rb = m0 + wm*128 + f*16 + kg*4;
    #pragma unroll
    for (int j=0; j<4; j++){
      int cc = n0 + wn*64 + j*16 + lm;
      #pragma unroll
      for (int r=0; r<4; r++)
        C[(size_t)(rb+r)*ldc + cc] = acc[f][j][r];
    }
  }
}

// ---------------- 128x128 fp16 MFMA NT GEMM (m97 structure) ----------------
__global__ __launch_bounds__(256) void gemm_f16nt(
    const u16* __restrict__ A, int lda,
    const u16* __restrict__ B, int ldb,
    float* __restrict__ C, int ldc,
    int K, int accflag)
{
  __shared__ u16 As[128*32];
  __shared__ u16 Bs[128*32];
  const int tid = threadIdx.x;
  const int lane = tid & 63;
  const int w = tid >> 6;
  const int wr = w >> 1, wc = w & 1;
  const int m0 = blockIdx.y*128, n0 = blockIdx.x*128;

  vf4 acc[4][4];
  #pragma unroll
  for (int i=0;i<4;i++)
    #pragma unroll
    for (int j=0;j<4;j++) acc[i][j] = (vf4){0.f,0.f,0.f,0.f};

  const int c0i = w*128 + lane;
  const int c1i = c0i + 64;
  const int r0i = c0i>>2, s0i = (c0i&3) ^ ((r0i>>1)&3);
  const int r1i = c1i>>2, s1i = (c1i&3) ^ ((r1i>>1)&3);
  const u16* gA0 = A + (size_t)(m0+r0i)*lda + s0i*8;
  const u16* gA1 = A + (size_t)(m0+r1i)*lda + s1i*8;
  const u16* gB0 = B + (size_t)(n0+r0i)*ldb + s0i*8;
  const u16* gB1 = B + (size_t)(n0+r1i)*ldb + s1i*8;
  u16* lA0 = As + w*1024;
  u16* lA1 = As + w*1024 + 512;
  u16* lB0 = Bs + w*1024;
  u16* lB1 = Bs + w*1024 + 512;

  const int kg = lane>>4, lm = lane&15;

  for (int k0=0; k0<K; k0+=32){
    __syncthreads();
    gload_lds16(gA0 + k0, lA0);
    gload_lds16(gA1 + k0, lA1);
    gload_lds16(gB0 + k0, lB0);
    gload_lds16(gB1 + k0, lB1);
    __syncthreads();
    f16x8 af[4], bfr[4];
    #pragma unroll
    for (int i=0;i<4;i++){
      int ra = wr*64 + i*16 + lm;
      int sa = kg ^ ((ra>>1)&3);
      af[i] = *(const f16x8*)(As + ra*32 + sa*8);
      int rb = wc*64 + i*16 + lm;
      int sb = kg ^ ((rb>>1)&3);
      bfr[i] = *(const f16x8*)(Bs + rb*32 + sb*8);
    }
    #pragma unroll
    for (int i=0;i<4;i++)
      #pragma unroll
      for (int j=0;j<4;j++)
        acc[i][j] = __builtin_amdgcn_mfma_f32_16x16x32_f16(af[i], bfr[j], acc[i][j], 0, 0, 0);
  }

  const int lhi = lane>>4;
  #pragma unroll
  for (int i=0;i<4;i++){
    int rbase = m0 + wr*64 + i*16 + lhi*4;
    #pragma unroll
    for (int j=0;j<4;j++){
      int cc = n0 + wc*64 + j*16 + lm;
      #pragma unroll
      for (int r=0;r<4;r++){
        float v = acc[i][j][r];
        float* pC = C + (size_t)(rbase+r)*ldc + cc;
        if (accflag) v += *pC;
        *pC = v;
      }
    }
  }
}

// ---------------- z projection GEMM, fp16 out with b0 bias folded ----------------
// C cols: [0,128)=zx (+b0x), [128,256)=zh (+b0h), [256,384)=zb. ldc=384, fp16.
__global__ __launch_bounds__(256) void gemm_zout(
    const u16* __restrict__ A,
    const u16* __restrict__ B,
    const float* __restrict__ b0x, const float* __restrict__ b0h,
    u16* __restrict__ Cz)
{
  __shared__ u16 As[128*32];
  __shared__ u16 Bs[128*32];
  const int tid = threadIdx.x;
  const int lane = tid & 63;
  const int w = tid >> 6;
  const int wr = w >> 1, wc = w & 1;
  const int m0 = blockIdx.y*128, n0 = blockIdx.x*128;

  vf4 acc[4][4];
  #pragma unroll
  for (int i=0;i<4;i++)
    #pragma unroll
    for (int j=0;j<4;j++) acc[i][j] = (vf4){0.f,0.f,0.f,0.f};

  const int c0i = w*128 + lane;
  const int c1i = c0i + 64;
  const int r0i = c0i>>2, s0i = (c0i&3) ^ ((r0i>>1)&3);
  const int r1i = c1i>>2, s1i = (c1i&3) ^ ((r1i>>1)&3);
  const u16* gA0 = A + (size_t)(m0+r0i)*256 + s0i*8;
  const u16* gA1 = A + (size_t)(m0+r1i)*256 + s1i*8;
  const u16* gB0 = B + (size_t)(n0+r0i)*256 + s0i*8;
  const u16* gB1 = B + (size_t)(n0+r1i)*256 + s1i*8;
  u16* lA0 = As + w*1024;
  u16* lA1 = As + w*1024 + 512;
  u16* lB0 = Bs + w*1024;
  u16* lB1 = Bs + w*1024 + 512;

  const int kg = lane>>4, lm = lane&15;

  for (int k0=0; k0<256; k0+=32){
    __syncthreads();
    gload_lds16(gA0 + k0, lA0);
    gload_lds16(gA1 + k0, lA1);
    gload_lds16(gB0 + k0, lB0);
    gload_lds16(gB1 + k0, lB1);
    __syncthreads();
    f16x8 af[4], bfr[4];
    #pragma unroll
    for (int i=0;i<4;i++){
      int ra = wr*64 + i*16 + lm;
      int sa = kg ^ ((ra>>1)&3);
      af[i] = *(const f16x8*)(As + ra*32 + sa*8);
      int rb = wc*64 + i*16 + lm;
      int sb = kg ^ ((rb>>1)&3);
      bfr[i] = *(const f16x8*)(Bs + rb*32 + sb*8);
    }
    #pragma unroll
    for (int i=0;i<4;i++)
      #pragma unroll
      for (int j=0;j<4;j++)
        acc[i][j] = __builtin_amdgcn_mfma_f32_16x16x32_f16(af[i], bfr[j], acc[i][j], 0, 0, 0);
  }

  const int lhi = lane>>4;
  #pragma unroll
  for (int i=0;i<4;i++){
    int rbase = m0 + wr*64 + i*16 + lhi*4;
    #pragma unroll
    for (int j=0;j<4;j++){
      int cc = n0 + wc*64 + j*16 + lm;
      float bias = (cc<128) ? b0x[cc] : (cc<256 ? b0h[cc-128] : 0.f);
      #pragma unroll
      for (int r=0;r<4;r++){
        _Float16 h = (_Float16)(acc[i][j][r] + bias);
        Cz[(size_t)(rbase+r)*384 + cc] = __builtin_bit_cast(u16, h);
      }
    }
  }
}

// ---------------- hyper LSTM cell ----------------
__global__ __launch_bounds__(256) void hyper_cell(
    const float* __restrict__ lin, const float* __restrict__ c_in,
    const float* __restrict__ lnh_w, const float* __restrict__ lnh_b,
    const float* __restrict__ lnc_w, const float* __restrict__ lnc_b,
    float* __restrict__ ht_out, float* __restrict__ ct_out,
    u16* __restrict__ hhyp16)
{
  int b=blockIdx.x, tid=threadIdx.x, lane=tid&63, w=tid>>6;
  __shared__ float ly[1024];
  __shared__ float red[4];
  float4 t = *(const float4*)(lin + (size_t)b*1024 + tid*4);
  float v[4]={t.x,t.y,t.z,t.w};
  float s = wave_sum(v[0]+v[1]+v[2]+v[3]);
  float mu = s*(1.f/256.f);
  float q=0.f;
  #pragma unroll
  for (int j=0;j<4;j++){ float d=v[j]-mu; q+=d*d; }
  q = wave_sum(q);
  float rs = rsqrtf(q*(1.f/256.f)+EPSV);
  int base = tid*4;
  #pragma unroll
  for (int j=0;j<4;j++) ly[base+j] = (v[j]-mu)*rs*lnh_w[base+j]+lnh_b[base+j];
  __syncthreads();
  float ig=ly[tid], fg=ly[256+tid], og=ly[512+tid], cc=ly[768+tid];
  float co = c_in[(size_t)b*LDT + 1024 + tid];
  float cn = sigf(fg+1.f)*co + sigf(ig)*tanhf(cc);
  float s2 = wave_sum(cn);
  if(lane==0) red[w]=s2;
  __syncthreads();
  float mu2=(red[0]+red[1]+red[2]+red[3])*(1.f/256.f);
  __syncthreads();
  float d = cn-mu2;
  float q2 = wave_sum(d*d);
  if(lane==0) red[w]=q2;
  __syncthreads();
  float rs2 = rsqrtf((red[0]+red[1]+red[2]+red[3])*(1.f/256.f)+EPSV);
  float hh = sigf(og)*tanhf(d*rs2*lnc_w[tid]+lnc_b[tid]);
  ht_out[(size_t)b*LDT+1024+tid]=hh;
  ct_out[(size_t)b*LDT+1024+tid]=cn;
  _Float16 h16 = (_Float16)hh;
  hhyp16[(size_t)b*256+tid] = __builtin_bit_cast(u16, h16);
}

// ---------------- scale_mfma: glin = sx*Wx + sh*Wh + bh  (MFMA dots, no LDS) ----------
// zcat16 [4096][384] fp16 (b0 folded), w1cat16 [3][4096][32] fp16 (L2-resident).
// 128x128 tile, 4 waves 2x2. Fragments read directly from global.
__global__ __launch_bounds__(256) void scale_mfma(
    const u16* __restrict__ zcat16,
    const u16* __restrict__ w1cat16,
    const float* __restrict__ Wx, const float* __restrict__ Wh,
    float* __restrict__ glin)
{
  const int tid = threadIdx.x;
  const int lane = tid & 63;
  const int w = tid >> 6;
  const int wr = w >> 1, wc = w & 1;
  const int m0 = blockIdx.y*128;
  const int n0 = blockIdx.x*128;
  const int g = n0 >> 10, gc = n0 & 1023;
  const int kg = lane>>4, lm = lane&15;

  vf4 gval[4][4];
  vf4 sacc[4][4];
  f16x8 af[4], bf[4];

  // ---- t = 0: sx ----
  #pragma unroll
  for (int i=0;i<4;i++){
    int row = m0 + wr*64 + i*16 + lm;
    af[i] = *(const f16x8*)(zcat16 + (size_t)row*384 + 0*128 + g*32 + kg*8);
  }
  #pragma unroll
  for (int j=0;j<4;j++){
    int col = gc + wc*64 + j*16 + lm;
    bf[j] = *(const f16x8*)(w1cat16 + 0*131072 + (size_t)(g*1024 + col)*32 + kg*8);
  }
  #pragma unroll
  for (int i=0;i<4;i++)
    #pragma unroll
    for (int j=0;j<4;j++){
      sacc[i][j] = (vf4){0.f,0.f,0.f,0.f};
      sacc[i][j] = __builtin_amdgcn_mfma_f32_16x16x32_f16(af[i], bf[j], sacc[i][j], 0, 0, 0);
    }
  #pragma unroll
  for (int i=0;i<4;i++){
    int rb = m0 + wr*64 + i*16 + kg*4;
    #pragma unroll
    for (int j=0;j<4;j++){
      int cc = n0 + wc*64 + j*16 + lm;
      #pragma unroll
      for (int r=0;r<4;r++)
        gval[i][j][r] = sacc[i][j][r] * Wx[(size_t)(rb+r)*4096 + cc];
    }
  }

  // ---- t = 1: sh ----
  #pragma unroll
  for (int i=0;i<4;i++){
    int row = m0 + wr*64 + i*16 + lm;
    af[i] = *(const f16x8*)(zcat16 + (size_t)row*384 + 1*128 + g*32 + kg*8);
  }
  #pragma unroll
  for (int j=0;j<4;j++){
    int col = gc + wc*64 + j*16 + lm;
    bf[j] = *(const f16x8*)(w1cat16 + 1*131072 + (size_t)(g*1024 + col)*32 + kg*8);
  }
  #pragma unroll
  for (int i=0;i<4;i++)
    #pragma unroll
    for (int j=0;j<4;j++){
      sacc[i][j] = (vf4){0.f,0.f,0.f,0.f};
      sacc[i][j] = __builtin_amdgcn_mfma_f32_16x16x32_f16(af[i], bf[j], sacc[i][j], 0, 0, 0);
    }
  #pragma unroll
  for (int i=0;i<4;i++){
    int rb = m0 + wr*64 + i*16 + kg*4;
    #pragma unroll
    for (int j=0;j<4;j++){
      int cc = n0 + wc*64 + j*16 + lm;
      #pragma unroll
      for (int r=0;r<4;r++)
        gval[i][j][r] += sacc[i][j][r] * Wh[(size_t)(rb+r)*4096 + cc];
    }
  }

  // ---- t = 2: bh ----
  #pragma unroll
  for (int i=0;i<4;i++){
    int row = m0 + wr*64 + i*16 + lm;
    af[i] = *(const f16x8*)(zcat16 + (size_t)row*384 + 2*128 + g*32 + kg*8);
  }
  #pragma unroll
  for (int j=0;j<4;j++){
    int col = gc + wc*64 + j*16 + lm;
    bf[j] = *(const f16x8*)(w1cat16 + 2*131072 + (size_t)(g*1024 + col)*32 + kg*8);
  }
  #pragma unroll
  for (int i=0;i<4;i++)
    #pragma unroll
    for (int j=0;j<4;j++){
      sacc[i][j] = (vf4){0.f,0.f,0.f,0.f};
      sacc[i][j] = __builtin_amdgcn_mfma_f32_16x16x32_f16(af[i], bf[j], sacc[i][j], 0, 0, 0);
    }

  // ---- write glin (in-place over Wx is safe: same thread read its elements above)
  #pragma unroll
  for (int i=0;i<4;i++){
    int rb = m0 + wr*64 + i*16 + kg*4;
    #pragma unroll
    for (int j=0;j<4;j++){
      int cc = n0 + wc*64 + j*16 + lm;
      #pragma unroll
      for (int r=0;r<4;r++)
        glin[(size_t)(rb+r)*4096 + cc] = gval[i][j][r] + sacc[i][j][r];
    }
  }
}

// ---------------- main LSTM cell ----------------
__global__ __launch_bounds__(256) void main_cell(
    const float* __restrict__ glin, const float* __restrict__ c_in,
    const float* __restrict__ lnh_w, const float* __restrict__ lnh_b,
    const float* __restrict__ lnc_w, const float* __restrict__ lnc_b,
    float* __restrict__ h_out, float* __restrict__ ht_out, float* __restrict__ ct_out)
{
  int b=blockIdx.x, tid=threadIdx.x, lane=tid&63, w=tid>>6;
  __shared__ float red[16];
  float v[4][4];
  #pragma unroll
  for (int g=0;g<4;g++){
    float4 t = *(const float4*)(glin + (size_t)b*4096 + g*1024 + tid*4);
    v[g][0]=t.x; v[g][1]=t.y; v[g][2]=t.z; v[g][3]=t.w;
  }
  float mu[4], rs[4];
  #pragma unroll
  for (int g=0;g<4;g++){
    float s = wave_sum(v[g][0]+v[g][1]+v[g][2]+v[g][3]);
    if(lane==0) red[g*4+w]=s;
  }
  __syncthreads();
  #pragma unroll
  for (int g=0;g<4;g++) mu[g]=(red[g*4]+red[g*4+1]+red[g*4+2]+red[g*4+3])*(1.f/1024.f);
  __syncthreads();
  #pragma unroll
  for (int g=0;g<4;g++){
    float q=0.f;
    #pragma unroll
    for (int j=0;j<4;j++){ float d=v[g][j]-mu[g]; q+=d*d; }
    q = wave_sum(q);
    if(lane==0) red[g*4+w]=q;
  }
  __syncthreads();
  #pragma unroll
  for (int g=0;g<4;g++) rs[g]=rsqrtf((red[g*4]+red[g*4+1]+red[g*4+2]+red[g*4+3])*(1.f/1024.f)+EPSV);
  int o0=tid*4;
  float y[4][4];
  #pragma unroll
  for (int g=0;g<4;g++)
    #pragma unroll
    for (int j=0;j<4;j++){
      int idx=g*1024+o0+j;
      y[g][j]=(v[g][j]-mu[g])*rs[g]*lnh_w[idx]+lnh_b[idx];
    }
  float4 ct = *(const float4*)(c_in + (size_t)b*LDT + o0);
  float co[4]={ct.x,ct.y,ct.z,ct.w};
  float cn[4];
  #pragma unroll
  for (int j=0;j<4;j++) cn[j]=sigf(y[1][j]+1.f)*co[j] + sigf(y[0][j])*tanhf(y[3][j]);
  float s = wave_sum(cn[0]+cn[1]+cn[2]+cn[3]);
  __syncthreads();
  if(lane==0) red[w]=s;
  __syncthreads();
  float muc=(red[0]+red[1]+red[2]+red[3])*(1.f/1024.f);
  __syncthreads();
  float q=0.f;
  #pragma unroll
  for (int j=0;j<4;j++){ float d=cn[j]-muc; q+=d*d; }
  q=wave_sum(q);
  if(lane==0) red[w]=q;
  __syncthreads();
  float rsc=rsqrtf((red[0]+red[1]+red[2]+red[3])*(1.f/1024.f)+EPSV);
  float h[4];
  #pragma unroll
  for (int j=0;j<4;j++) h[j]=sigf(y[2][j])*tanhf((cn[j]-muc)*rsc*lnc_w[o0+j]+lnc_b[o0+j]);
  float4 hv; hv.x=h[0]; hv.y=h[1]; hv.z=h[2]; hv.w=h[3];
  float4 cv; cv.x=cn[0]; cv.y=cn[1]; cv.z=cn[2]; cv.w=cn[3];
  *(float4*)(h_out +(size_t)b*1024+o0) = hv;
  *(float4*)(ht_out+(size_t)b*LDT +o0) = hv;
  *(float4*)(ct_out+(size_t)b*LDT +o0) = cv;
}

extern "C" void kernel_launch(void* const* d_in, const int* in_sizes, int n_in,
                              void* d_out, int out_size, void* d_ws, size_t ws_size,
                              hipStream_t stream) {
  (void)in_sizes; (void)n_in; (void)out_size; (void)ws_size;
  const float* x         = (const float*)d_in[0];
  const float* h_total   = (const float*)d_in[1];
  const float* c_total   = (const float*)d_in[2];
  const float* hyp_w_ih  = (const float*)d_in[3];
  const float* hyp_w_hh  = (const float*)d_in[4];
  const float* hyp_lnh_w = (const float*)d_in[5];
  const float* hyp_lnh_b = (const float*)d_in[6];
  const float* hyp_lnc_w = (const float*)d_in[7];
  const float* hyp_lnc_b = (const float*)d_in[8];
  const float* w_ih      = (const float*)d_in[9];
  const float* w_hh      = (const float*)d_in[10];
  const float* lnh_w     = (const float*)d_in[11];
  const float* lnh_b     = (const float*)d_in[12];
  const float* lnc_w     = (const float*)d_in[13];
  const float* lnc_b     = (const float*)d_in[14];
  const float* sx_w0     = (const float*)d_in[15];
  const float* sx_b0     = (const float*)d_in[16];
  const float* sx_w1     = (const float*)d_in[17];
  const float* sh_w0     = (const float*)d_in[18];
  const float* sh_b0     = (const float*)d_in[19];
  const float* sh_w1     = (const float*)d_in[20];
  const float* bh_w0     = (const float*)d_in[21];
  const float* bh_w1     = (const float*)d_in[22];

  float* out    = (float*)d_out;
  float* h_out  = out;
  float* ht_out = out + (size_t)BB*1024;
  float* ct_out = ht_out + (size_t)BB*LDT;

  char* p = (char*)d_ws;
  float* lin    = (float*)p; p += (size_t)4096*1024*4;
  float* Wx     = (float*)p; p += (size_t)4096*4096*4;
  float* Wh     = (float*)p; p += (size_t)4096*4096*4;
  u16* Hbig     = (u16*)p;   p += (size_t)4096*1024*2;
  u16* Wihb     = (u16*)p;   p += (size_t)4096*512*2;
  u16* Whhb     = (u16*)p;   p += (size_t)4096*1024*2;
  u16* XHhyp    = (u16*)p;   p += (size_t)4096*768*2;
  u16* Whyp     = (u16*)p;   p += (size_t)1024*768*2;
  u16* Hhyp16   = (u16*)p;   p += (size_t)4096*256*2;
  u16* Zw       = (u16*)p;   p += (size_t)384*256*2;
  u16* zcat16   = (u16*)p;   p += (size_t)4096*384*2;
  u16* w1cat16  = (u16*)p;   p += (size_t)3*131072*2;

  // merged fp16 conversions (5 launches)
  cvt_acts <<<dim3(7,4096),64,0,stream>>>(x, h_total, XHhyp, Hbig);
  cvt_wmain<<<dim3(6,4096),64,0,stream>>>(w_ih, w_hh, Wihb, Whhb);
  cvt_whyp <<<dim3(3,1024),64,0,stream>>>(hyp_w_ih, hyp_w_hh, Whyp);
  cvt_zw   <<<dim3(1,384),64,0,stream>>>(sx_w0, sh_w0, bh_w0, Zw);
  cvt_w1   <<<384,256,0,stream>>>(sx_w1, sh_w1, bh_w1, w1cat16);

  // hyper linear (K=768)
  gemm_f16nt<<<dim3(8,32),256,0,stream>>>(XHhyp,768, Whyp,768, lin,1024, 768, 0);
  // main big GEMMs
  gemm256<<<dim3(16,16),512,0,stream>>>(XHhyp,768, Wihb,512, Wx,4096, 512);
  gemm256<<<dim3(16,16),512,0,stream>>>(Hbig,1024, Whhb,1024, Wh,4096, 1024);

  // hyper cell (also emits h_hyper_new in fp16)
  hyper_cell<<<4096,256,0,stream>>>(lin, c_total, hyp_lnh_w, hyp_lnh_b, hyp_lnc_w, hyp_lnc_b,
                                    ht_out, ct_out, Hhyp16);

  // z projections, fp16 out with b0 folded
  gemm_zout<<<dim3(3,32),256,0,stream>>>(Hhyp16, Zw, sx_b0, sh_b0, zcat16);

  // fused scale+apply (glin overwrites Wx)
  scale_mfma<<<dim3(32,32),256,0,stream>>>(zcat16, w1cat16, Wx, Wh, Wx);

  main_cell<<<4096,256,0,stream>>>(Wx, c_total, lnh_w, lnh_b, lnc_w, lnc_b, h_out, ht_out, ct_out);
}